// Round 9
// baseline (863.835 us; speedup 1.0000x reference)
//
#include <hip/hip_runtime.h>
#include <hip/hip_bf16.h>

using u16 = unsigned short;
using u32 = unsigned int;

#define NN 100000
#define NE 1000000

typedef __attribute__((ext_vector_type(8))) short bfrag;
typedef __attribute__((ext_vector_type(4))) float ffrag;

#define BF16ONE2 0x3F803F80u

__device__ __forceinline__ float bf2f(u16 u) { return __uint_as_float(((u32)u) << 16); }
__device__ __forceinline__ u16 f2bf(float f) {
  u32 x = __float_as_uint(f);
  return (u16)((x + 0x7fffu + ((x >> 16) & 1u)) >> 16);
}
__device__ __forceinline__ float rdv(const void* p, long i, int f) {
  return f ? bf2f(((const u16*)p)[i]) : ((const float*)p)[i];
}
__device__ __forceinline__ void acc8(float* a, uint4 v, float w) {
  a[0] = fmaf(w, __uint_as_float(v.x << 16), a[0]);
  a[1] = fmaf(w, __uint_as_float(v.x & 0xffff0000u), a[1]);
  a[2] = fmaf(w, __uint_as_float(v.y << 16), a[2]);
  a[3] = fmaf(w, __uint_as_float(v.y & 0xffff0000u), a[3]);
  a[4] = fmaf(w, __uint_as_float(v.z << 16), a[4]);
  a[5] = fmaf(w, __uint_as_float(v.z & 0xffff0000u), a[5]);
  a[6] = fmaf(w, __uint_as_float(v.w << 16), a[6]);
  a[7] = fmaf(w, __uint_as_float(v.w & 0xffff0000u), a[7]);
}

// wq (u16) element offsets
#define OWXT 0
#define OWPRE 16384
#define OWD1 32768
#define OW11 49152
#define OV21 65536
#define OWD2 81920
#define OW12 98304
#define OV22 114688
#define OWPOST 131072
#define OWET 147456

struct PrepArgs { const void* in[16]; };

__global__ void k_prep(PrepArgs a, const u32* __restrict__ gp, u16* __restrict__ wq,
                       float* __restrict__ wf) {
  int t = blockIdx.x * 256 + threadIdx.x;
  int f = (gp[0] == BF16ONE2) ? 1 : 0;
  if (t < 16384) {
    int o = t >> 7, k = t & 127;
    int ko = k * 128 + o;
    int ok = o * 128 + k;
    wq[OWXT + ok] = f2bf(rdv(a.in[0], ko, f));
    wq[OWPRE + ok] = f2bf(rdv(a.in[2], ko, f));
    float c0 = rdv(a.in[6], ko, f);
    float c1 = rdv(a.in[6], 16384 + ko, f);
    float c2 = rdv(a.in[6], 32768 + ko, f);
    wq[OWD1 + ok] = f2bf(c0 - c2);
    wq[OW11 + ok] = f2bf(c1);
    wq[OV21 + ok] = f2bf(2.f * c2);
    float d0 = rdv(a.in[8], ko, f);
    float d1 = rdv(a.in[8], 16384 + ko, f);
    float d2 = rdv(a.in[8], 32768 + ko, f);
    wq[OWD2 + ok] = f2bf(d0 - d2);
    wq[OW12 + ok] = f2bf(d1);
    wq[OV22 + ok] = f2bf(2.f * d2);
    wq[OWPOST + ok] = f2bf(rdv(a.in[10], ko, f));
  }
  if (t < 4096) {
    int o = t >> 5, k = t & 31;
    wq[OWET + o * 32 + k] = (k < 16) ? f2bf(rdv(a.in[0], (long)(128 + k) * 128 + o, f)) : (u16)0;
  }
  if (t < 1281) {
    int s = t >> 7, j = t & 127;
    const int map[11] = {1, 3, 4, 5, 7, 9, 11, 12, 13, 14, 15};
    wf[t] = rdv(a.in[map[s]], j, f);
  }
}

// ---------------- histogram + rank (full occupancy: 4 VGPR, no LDS) ----------------
__global__ void k_hist(const int* __restrict__ ei, int* cnt, int* deg, int* rank) {
  int e = blockIdx.x * 256 + threadIdx.x;
  if (e >= NE) return;
  atomicAdd(&deg[ei[e]], 1);
  rank[e] = atomicAdd(&cnt[ei[NE + e]], 1);
}

// ---------------- exclusive scan ----------------
__global__ void k_scan1(const int* __restrict__ cnt, int* off, int* bsum) {
  __shared__ int s[1024];
  int t = threadIdx.x;
  int g = blockIdx.x * 1024 + t;
  int v = (g < NN) ? cnt[g] : 0;
  s[t] = v;
  __syncthreads();
  for (int st = 1; st < 1024; st <<= 1) {
    int x = (t >= st) ? s[t - st] : 0;
    __syncthreads();
    s[t] += x;
    __syncthreads();
  }
  if (g < NN) off[g] = s[t] - v;
  if (t == 1023) bsum[blockIdx.x] = s[t];
}

__global__ void k_scan23(int* off, const int* __restrict__ bsum,
                         const int* __restrict__ deg, float* __restrict__ dis, int nb) {
  __shared__ int s[128];
  int t = threadIdx.x;
  int v = 0;
  if (t < 128) {
    v = (t < nb) ? bsum[t] : 0;
    s[t] = v;
  }
  __syncthreads();
  for (int st = 1; st < 128; st <<= 1) {
    int x = (t >= st && t < 128) ? s[t - st] : 0;
    __syncthreads();
    if (t < 128) s[t] += x;
    __syncthreads();
  }
  if (t < 128) s[t] -= v;
  __syncthreads();
  int pre = s[blockIdx.x];
  int g = blockIdx.x * 1024 + t;
  if (g < NN) {
    off[g] += pre;
    int d = deg[g];
    dis[g] = d > 0 ? rsqrtf((float)d) : 0.f;
  }
  if (g == 0) off[NN] = NE;
}

// ---------------- CSR placement (atomic-free via rank) ----------------
__global__ void k_place(const int* __restrict__ ei, const int* __restrict__ off,
                        const int* __restrict__ rank, int* crow, int* ceid) {
  int e = blockIdx.x * 256 + threadIdx.x;
  if (e >= NE) return;
  int r = ei[e], c = ei[NE + e];
  int p = off[c] + rank[e];
  crow[p] = r;
  ceid[p] = e;
}

// ------------- SpMM: 2 nodes/wave, 2 half-chains x 16 lanes x uint4 -------------
// BN=1: gathered values pass through relu(a*v+c) (bn table in ab[0..127]=a, [128..255]=c)
template <int BN>
__global__ __launch_bounds__(256) void k_spmm(const u16* __restrict__ src,
                                              u16* __restrict__ dst,
                                              const int* __restrict__ off,
                                              const int* __restrict__ crow,
                                              const float* __restrict__ dis,
                                              const u16* __restrict__ G, int relu,
                                              const float* __restrict__ ab) {
  int t = threadIdx.x;
  int node = blockIdx.x * 8 + (t >> 5);
  if (node >= NN) return;
  int l = t & 31;
  int half = l >> 4;
  int c = (l & 15) * 8;
  int p0 = off[node], p1 = off[node + 1];
  float a[8];
#pragma unroll
  for (int j = 0; j < 8; j++) a[j] = 0.f;
  float bna[8], bnc[8];
  if (BN) {
    float4 a0 = *(const float4*)(ab + c);
    float4 a1 = *(const float4*)(ab + c + 4);
    float4 c0 = *(const float4*)(ab + 128 + c);
    float4 c1 = *(const float4*)(ab + 132 + c);
    bna[0] = a0.x; bna[1] = a0.y; bna[2] = a0.z; bna[3] = a0.w;
    bna[4] = a1.x; bna[5] = a1.y; bna[6] = a1.z; bna[7] = a1.w;
    bnc[0] = c0.x; bnc[1] = c0.y; bnc[2] = c0.z; bnc[3] = c0.w;
    bnc[4] = c1.x; bnc[5] = c1.y; bnc[6] = c1.z; bnc[7] = c1.w;
  }
  const u16* sp = src + c;
  auto accv = [&](uint4 v, float w) {
    float f[8];
    f[0] = __uint_as_float(v.x << 16);
    f[1] = __uint_as_float(v.x & 0xffff0000u);
    f[2] = __uint_as_float(v.y << 16);
    f[3] = __uint_as_float(v.y & 0xffff0000u);
    f[4] = __uint_as_float(v.z << 16);
    f[5] = __uint_as_float(v.z & 0xffff0000u);
    f[6] = __uint_as_float(v.w << 16);
    f[7] = __uint_as_float(v.w & 0xffff0000u);
    if (BN) {
#pragma unroll
      for (int j = 0; j < 8; j++) f[j] = fmaxf(fmaf(bna[j], f[j], bnc[j]), 0.f);
    }
#pragma unroll
    for (int j = 0; j < 8; j++) a[j] = fmaf(w, f[j], a[j]);
  };
  if (dis) {
    float nc = -dis[node];
    int p = p0 + half;
    for (; p + 6 < p1; p += 8) {
      int r0 = crow[p], r1 = crow[p + 2], r2 = crow[p + 4], r3 = crow[p + 6];
      float w0 = nc * dis[r0], w1 = nc * dis[r1];
      float w2 = nc * dis[r2], w3 = nc * dis[r3];
      uint4 v0 = *(const uint4*)(sp + (long)r0 * 128);
      uint4 v1 = *(const uint4*)(sp + (long)r1 * 128);
      uint4 v2 = *(const uint4*)(sp + (long)r2 * 128);
      uint4 v3 = *(const uint4*)(sp + (long)r3 * 128);
      accv(v0, w0);
      accv(v1, w1);
      accv(v2, w2);
      accv(v3, w3);
    }
    for (; p < p1; p += 2) {
      int r = crow[p];
      accv(*(const uint4*)(sp + (long)r * 128), nc * dis[r]);
    }
  } else {
    int p = p0 + half;
    for (; p + 6 < p1; p += 8) {
      int r0 = crow[p], r1 = crow[p + 2], r2 = crow[p + 4], r3 = crow[p + 6];
      uint4 v0 = *(const uint4*)(sp + (long)r0 * 128);
      uint4 v1 = *(const uint4*)(sp + (long)r1 * 128);
      uint4 v2 = *(const uint4*)(sp + (long)r2 * 128);
      uint4 v3 = *(const uint4*)(sp + (long)r3 * 128);
      accv(v0, 1.f);
      accv(v1, 1.f);
      accv(v2, 1.f);
      accv(v3, 1.f);
    }
    for (; p < p1; p += 2) accv(*(const uint4*)(sp + (long)crow[p] * 128), 1.f);
  }
#pragma unroll
  for (int j = 0; j < 8; j++) a[j] += __shfl_xor(a[j], 16);
  if (half) return;
  if (G) acc8(a, *(const uint4*)(G + (long)node * 128 + c), 1.f);
  if (relu) {
#pragma unroll
    for (int j = 0; j < 8; j++) a[j] = fmaxf(a[j], 0.f);
  }
  uint4 o;
  o.x = (u32)f2bf(a[0]) | ((u32)f2bf(a[1]) << 16);
  o.y = (u32)f2bf(a[2]) | ((u32)f2bf(a[3]) << 16);
  o.z = (u32)f2bf(a[4]) | ((u32)f2bf(a[5]) << 16);
  o.w = (u32)f2bf(a[6]) | ((u32)f2bf(a[7]) << 16);
  *(uint4*)(dst + (long)node * 128 + c) = o;
}

// ------------- edge_attr segment-sum -------------
__global__ __launch_bounds__(256) void k_asum(const void* __restrict__ eattr,
                                              const u32* __restrict__ gp,
                                              u16* __restrict__ asum,
                                              const int* __restrict__ off,
                                              const int* __restrict__ ceid) {
  int t = blockIdx.x * 256 + threadIdx.x;
  int node = t >> 4;
  if (node >= NN) return;
  int j = t & 15;
  int p0 = off[node], p1 = off[node + 1];
  float a = 0.f;
  if (gp[0] == BF16ONE2) {
    const u16* e16 = (const u16*)eattr;
    int p = p0;
    for (; p + 4 <= p1; p += 4) {
      float v0 = bf2f(e16[(long)ceid[p] * 16 + j]);
      float v1 = bf2f(e16[(long)ceid[p + 1] * 16 + j]);
      float v2 = bf2f(e16[(long)ceid[p + 2] * 16 + j]);
      float v3 = bf2f(e16[(long)ceid[p + 3] * 16 + j]);
      a += v0 + v1 + v2 + v3;
    }
    for (; p < p1; p++) a += bf2f(e16[(long)ceid[p] * 16 + j]);
  } else {
    const float* e32 = (const float*)eattr;
    int p = p0;
    for (; p + 4 <= p1; p += 4) {
      float v0 = e32[(long)ceid[p] * 16 + j];
      float v1 = e32[(long)ceid[p + 1] * 16 + j];
      float v2 = e32[(long)ceid[p + 2] * 16 + j];
      float v3 = e32[(long)ceid[p + 3] * 16 + j];
      a += v0 + v1 + v2 + v3;
    }
    for (; p < p1; p++) a += e32[(long)ceid[p] * 16 + j];
  }
  asum[(long)node * 32 + j] = f2bf(a);
  asum[(long)node * 32 + 16 + j] = 0;
}

// ------------- MFMA GEMM, weight-stationary regs + LDS-staged A -------------
struct MArgs {
  const void* A0; const u16* W0T; int a0raw;
  const u16* A1; const u16* W1T;
  const u16* W2T; u16* out2;
  const float* bias;
  const u16* G;
  u16* out;
  const int* cnt;
  const u32* gp;
  float* part;
  const float* bnab;  // if non-null: A0 := relu(a*A0+c) during staging (bf16 A0 only)
  int mode;
};

#define ASTRIDE 136
#define ESTRIDE 132

template <int DUAL, int K0, int ROWS>
__device__ __forceinline__ void mgemm_body(const MArgs& m, int blk) {
  constexpr int RT = ROWS / 16;
  constexpr int TPR = 256 / ROWS;
  constexpr int SEGW = K0 / TPR;
  constexpr int NKB0 = K0 / 32;
  __shared__ __align__(16) u16 sA[ROWS * ASTRIDE];
  int tid = threadIdx.x;
  int wv = tid >> 6, lane = tid & 63;
  int col16 = lane & 15, quad = lane >> 4;
  int r0 = blk * ROWS;

  ffrag acc[RT * 2];
#pragma unroll
  for (int i = 0; i < RT * 2; i++)
#pragma unroll
    for (int g = 0; g < 4; g++) acc[i][g] = 0.f;

  {
    int row = tid / TPR, seg = tid % TPR;
    int ra = r0 + row;
    if (ra >= NN) ra = NN - 1;
    bool f32a = m.a0raw && (m.gp[0] != BF16ONE2);
    if (f32a) {
      const float* gs = (const float*)m.A0 + (long)ra * K0 + seg * SEGW;
      u32* lp = (u32*)(sA + row * ASTRIDE + seg * SEGW);
#pragma unroll
      for (int e = 0; e < SEGW / 8; e++) {
        float4 v0 = *(const float4*)(gs + e * 8);
        float4 v1 = *(const float4*)(gs + e * 8 + 4);
        lp[e * 4 + 0] = (u32)f2bf(v0.x) | ((u32)f2bf(v0.y) << 16);
        lp[e * 4 + 1] = (u32)f2bf(v0.z) | ((u32)f2bf(v0.w) << 16);
        lp[e * 4 + 2] = (u32)f2bf(v1.x) | ((u32)f2bf(v1.y) << 16);
        lp[e * 4 + 3] = (u32)f2bf(v1.z) | ((u32)f2bf(v1.w) << 16);
      }
    } else if (m.bnab) {
      const u16* gs = (const u16*)m.A0 + (long)ra * K0 + seg * SEGW;
      u32* lp = (u32*)(sA + row * ASTRIDE + seg * SEGW);
#pragma unroll
      for (int e = 0; e < SEGW / 8; e++) {
        int cb = seg * SEGW + e * 8;
        uint4 v = *(const uint4*)(gs + e * 8);
        float4 ba0 = *(const float4*)(m.bnab + cb);
        float4 ba1 = *(const float4*)(m.bnab + cb + 4);
        float4 bc0 = *(const float4*)(m.bnab + 128 + cb);
        float4 bc1 = *(const float4*)(m.bnab + 132 + cb);
        float f0 = fmaxf(fmaf(ba0.x, __uint_as_float(v.x << 16), bc0.x), 0.f);
        float f1 = fmaxf(fmaf(ba0.y, __uint_as_float(v.x & 0xffff0000u), bc0.y), 0.f);
        float f2 = fmaxf(fmaf(ba0.z, __uint_as_float(v.y << 16), bc0.z), 0.f);
        float f3 = fmaxf(fmaf(ba0.w, __uint_as_float(v.y & 0xffff0000u), bc0.w), 0.f);
        float f4 = fmaxf(fmaf(ba1.x, __uint_as_float(v.z << 16), bc1.x), 0.f);
        float f5 = fmaxf(fmaf(ba1.y, __uint_as_float(v.z & 0xffff0000u), bc1.y), 0.f);
        float f6 = fmaxf(fmaf(ba1.z, __uint_as_float(v.w << 16), bc1.z), 0.f);
        float f7 = fmaxf(fmaf(ba1.w, __uint_as_float(v.w & 0xffff0000u), bc1.w), 0.f);
        lp[e * 4 + 0] = (u32)f2bf(f0) | ((u32)f2bf(f1) << 16);
        lp[e * 4 + 1] = (u32)f2bf(f2) | ((u32)f2bf(f3) << 16);
        lp[e * 4 + 2] = (u32)f2bf(f4) | ((u32)f2bf(f5) << 16);
        lp[e * 4 + 3] = (u32)f2bf(f6) | ((u32)f2bf(f7) << 16);
      }
    } else {
      const u16* gs = (const u16*)m.A0 + (long)ra * K0 + seg * SEGW;
      uint4* lp = (uint4*)(sA + row * ASTRIDE + seg * SEGW);
#pragma unroll
      for (int e = 0; e < SEGW / 8; e++) lp[e] = *(const uint4*)(gs + e * 8);
    }
  }
  bfrag b0[2][NKB0];
#pragma unroll
  for (int c = 0; c < 2; c++)
#pragma unroll
    for (int kb = 0; kb < NKB0; kb++)
      b0[c][kb] = *(const bfrag*)(m.W0T + (long)(wv * 32 + c * 16 + col16) * K0 + kb * 32 + quad * 8);
  __syncthreads();
#pragma unroll
  for (int kb = 0; kb < NKB0; kb++)
#pragma unroll
    for (int rt = 0; rt < RT; rt++) {
      bfrag af = *(const bfrag*)(sA + (rt * 16 + col16) * ASTRIDE + kb * 32 + quad * 8);
      acc[rt * 2 + 0] = __builtin_amdgcn_mfma_f32_16x16x32_bf16(af, b0[0][kb], acc[rt * 2 + 0], 0, 0, 0);
      acc[rt * 2 + 1] = __builtin_amdgcn_mfma_f32_16x16x32_bf16(af, b0[1][kb], acc[rt * 2 + 1], 0, 0, 0);
    }

  ffrag acc2[DUAL ? RT * 2 : 1];
  if constexpr (DUAL) {
#pragma unroll
    for (int i = 0; i < RT * 2; i++)
#pragma unroll
      for (int g = 0; g < 4; g++) acc2[i][g] = 0.f;
    __syncthreads();
    {
      int row = tid / TPR, seg = tid % TPR;
      int ra = r0 + row;
      if (ra >= NN) ra = NN - 1;
      const u16* gs = m.A1 + (long)ra * 128 + seg * SEGW;
      uint4* lp = (uint4*)(sA + row * ASTRIDE + seg * SEGW);
#pragma unroll
      for (int e = 0; e < SEGW / 8; e++) lp[e] = *(const uint4*)(gs + e * 8);
    }
    bfrag b1[2][4], b2[2][4];
#pragma unroll
    for (int c = 0; c < 2; c++)
#pragma unroll
      for (int kb = 0; kb < 4; kb++) {
        b1[c][kb] = *(const bfrag*)(m.W1T + (long)(wv * 32 + c * 16 + col16) * 128 + kb * 32 + quad * 8);
        b2[c][kb] = *(const bfrag*)(m.W2T + (long)(wv * 32 + c * 16 + col16) * 128 + kb * 32 + quad * 8);
      }
    __syncthreads();
#pragma unroll
    for (int kb = 0; kb < 4; kb++)
#pragma unroll
      for (int rt = 0; rt < RT; rt++) {
        bfrag af = *(const bfrag*)(sA + (rt * 16 + col16) * ASTRIDE + kb * 32 + quad * 8);
        acc[rt * 2 + 0] = __builtin_amdgcn_mfma_f32_16x16x32_bf16(af, b1[0][kb], acc[rt * 2 + 0], 0, 0, 0);
        acc[rt * 2 + 1] = __builtin_amdgcn_mfma_f32_16x16x32_bf16(af, b1[1][kb], acc[rt * 2 + 1], 0, 0, 0);
        acc2[rt * 2 + 0] = __builtin_amdgcn_mfma_f32_16x16x32_bf16(af, b2[0][kb], acc2[rt * 2 + 0], 0, 0, 0);
        acc2[rt * 2 + 1] = __builtin_amdgcn_mfma_f32_16x16x32_bf16(af, b2[1][kb], acc2[rt * 2 + 1], 0, 0, 0);
      }
  }

  __syncthreads();
#pragma unroll
  for (int rt = 0; rt < RT; rt++)
#pragma unroll
    for (int c = 0; c < 2; c++) {
      int col = wv * 32 + c * 16 + col16;
      float bj = m.bias ? m.bias[col] : 0.f;
#pragma unroll
      for (int g = 0; g < 4; g++) {
        int r = r0 + rt * 16 + quad * 4 + g;
        float v = acc[rt * 2 + c][g];
        if (m.G && r < NN) v += bf2f(m.G[(long)r * 128 + col]);
        if (m.mode == 2) {
          int cc = (r < NN) ? m.cnt[r] : 0;
          v = (v + (float)cc * bj) / (float)(cc > 1 ? cc : 1);
        } else {
          v += bj;
        }
        sA[(rt * 16 + quad * 4 + g) * ESTRIDE + col] = f2bf(v);
      }
    }
  __syncthreads();
  {
    constexpr int CPT = 128 / TPR;
    int rr = tid / TPR, d = tid % TPR;
    int rowg = r0 + rr;
    if (rowg < NN) {
      const u16* sp2 = sA + rr * ESTRIDE + d * CPT;
      uint4* o = (uint4*)(m.out + (long)rowg * 128 + d * CPT);
#pragma unroll
      for (int e = 0; e < CPT / 8; e++) {
        const uint2* s2 = (const uint2*)(sp2 + e * 8);
        uint2 lo = s2[0], hi = s2[1];
        o[e] = make_uint4(lo.x, lo.y, hi.x, hi.y);
      }
    }
  }
  if (m.part) {
    __shared__ float ps[256], pq[256];
    int col = tid & 127, hf = tid >> 7;
    float s = 0.f, q = 0.f;
#pragma unroll
    for (int r = 0; r < ROWS / 2; r++) {
      int rr = hf * (ROWS / 2) + r;
      if (r0 + rr < NN) {
        float v = bf2f(sA[rr * ESTRIDE + col]);
        s += v;
        q += v * v;
      }
    }
    ps[tid] = s;
    pq[tid] = q;
    __syncthreads();
    if (tid < 128) {
      m.part[(long)blk * 256 + tid] = ps[tid] + ps[tid + 128];
      m.part[(long)blk * 256 + 128 + tid] = pq[tid] + pq[tid + 128];
    }
  }
  if constexpr (DUAL) {
    __syncthreads();
#pragma unroll
    for (int rt = 0; rt < RT; rt++)
#pragma unroll
      for (int c = 0; c < 2; c++) {
        int col = wv * 32 + c * 16 + col16;
#pragma unroll
        for (int g = 0; g < 4; g++)
          sA[(rt * 16 + quad * 4 + g) * ESTRIDE + col] = f2bf(acc2[rt * 2 + c][g]);
      }
    __syncthreads();
    constexpr int CPT = 128 / TPR;
    int rr = tid / TPR, d = tid % TPR;
    int rowg = r0 + rr;
    if (rowg < NN) {
      const u16* sp2 = sA + rr * ESTRIDE + d * CPT;
      uint4* o = (uint4*)(m.out2 + (long)rowg * 128 + d * CPT);
#pragma unroll
      for (int e = 0; e < CPT / 8; e++) {
        const uint2* s2 = (const uint2*)(sp2 + e * 8);
        uint2 lo = s2[0], hi = s2[1];
        o[e] = make_uint4(lo.x, lo.y, hi.x, hi.y);
      }
    }
  }
}

template <int DUAL, int K0, int ROWS>
__global__ __launch_bounds__(256) void k_mgemm(MArgs m) {
  mgemm_body<DUAL, K0, ROWS>(m, blockIdx.x);
}

// ------------- reduce stats partials (atomic-free) -------------
__global__ void k_red(const float* __restrict__ part, float* stats, int nblk) {
  int tid = threadIdx.x;
  int j = blockIdx.x * 32 + (tid & 31);
  int ch = tid >> 5;
  float s = 0.f;
  for (int b = ch; b < nblk; b += 8) s += part[(long)b * 256 + j];
  __shared__ float sh[256];
  sh[tid] = s;
  __syncthreads();
  if (tid < 32) {
    float t = 0.f;
#pragma unroll
    for (int i = 0; i < 8; i++) t += sh[i * 32 + tid];
    stats[blockIdx.x * 32 + tid] = t;
  }
}

__global__ void k_bnfin(const float* __restrict__ stats, const float* __restrict__ gamma,
                        const float* __restrict__ beta, float* ab) {
  int j = threadIdx.x;
  if (j >= 128) return;
  float m = stats[j] * (1.f / (float)NN);
  float v = fmaxf(stats[128 + j] * (1.f / (float)NN) - m * m, 0.f);
  float a = gamma[j] * rsqrtf(v + 1e-5f);
  float c = beta[j] - m * a;
  ab[j] = a;
  ab[128 + j] = c;
}

__global__ void k_out(const u16* __restrict__ z, const float* __restrict__ ab,
                      const float* __restrict__ wout, const float* __restrict__ bout,
                      const u32* __restrict__ gp, void* __restrict__ y) {
  int node = blockIdx.x * 4 + (threadIdx.x >> 6);
  if (node >= NN) return;
  int lane = threadIdx.x & 63;
  float s = 0.f;
#pragma unroll
  for (int c = lane; c < 128; c += 64) {
    float zz = bf2f(z[(long)node * 128 + c]);
    float h = fmaxf(ab[c] * zz + ab[128 + c], 0.f);
    s += h * wout[c];
  }
#pragma unroll
  for (int o = 32; o > 0; o >>= 1) s += __shfl_down(s, o);
  if (lane == 0) {
    float r = s + bout[0];
    if (gp[0] == BF16ONE2) ((u16*)y)[node] = f2bf(r);
    else ((float*)y)[node] = r;
  }
}

extern "C" void kernel_launch(void* const* d_in, const int* in_sizes, int n_in,
                              void* d_out, int out_size, void* d_ws, size_t ws_size,
                              hipStream_t stream) {
  const void* x = d_in[0];
  const int* ei = (const int*)d_in[1];
  const void* eattr = d_in[2];
  const u32* gp = (const u32*)d_in[7];
  (void)in_sizes; (void)n_in; (void)out_size; (void)ws_size;

  char* w = (char*)d_ws;
  size_t p = 0;
  auto alloc = [&](size_t b) { size_t r = p; p += (b + 255) & ~(size_t)255; return r; };
  size_t o_cnt = alloc((size_t)NN * 4);
  size_t o_deg = alloc((size_t)NN * 4);
  size_t o_zero_end = p;
  size_t o_dis = alloc((size_t)NN * 4);
  size_t o_off = alloc((size_t)(NN + 1) * 4);
  size_t o_bsum = alloc(1024 * 4);
  size_t o_stat = alloc(512 * 4);
  size_t o_ab = alloc(512 * 4);
  size_t o_wq = alloc((size_t)151552 * 2);
  size_t o_wf = alloc((size_t)1281 * 4);
  size_t o_crow = alloc((size_t)NE * 4);
  size_t o_asum = alloc((size_t)NN * 32 * 2);  // also hosts rank (4MB <= 6.4MB)
  size_t o_part = alloc((size_t)782 * 256 * 4);
  size_t o_Bx = alloc((size_t)NN * 128 * 2);
  size_t o_Bt = alloc((size_t)NN * 128 * 2);

  int* cnt = (int*)(w + o_cnt);
  int* deg = (int*)(w + o_deg);
  float* dis = (float*)(w + o_dis);
  int* off = (int*)(w + o_off);
  int* bsum = (int*)(w + o_bsum);
  float* statA = (float*)(w + o_stat);
  float* statB = statA + 256;
  float* abA = (float*)(w + o_ab);
  float* abB = abA + 256;
  u16* wq = (u16*)(w + o_wq);
  float* wf = (float*)(w + o_wf);
  int* crow = (int*)(w + o_crow);
  u16* asum = (u16*)(w + o_asum);
  float* part = (float*)(w + o_part);
  u16* Bx = (u16*)(w + o_Bx);
  u16* Bt = (u16*)(w + o_Bt);
  int* rank = (int*)asum;  // dead before k_asum writes asum
  int* ceid = (int*)Bt;    // dead before Bt first written (after k_asum)

  hipMemsetAsync(w + o_cnt, 0, o_zero_end - o_cnt, stream);

  int gE = (NE + 255) / 256;
  int nb = (NN + 1023) / 1024;
  int gS = (NN + 7) / 8;
  int gG1 = (NN + 127) / 128;  // 782
  int gG2 = (NN + 63) / 64;    // 1563

  {
    PrepArgs a;
    for (int i = 0; i < 16; i++) a.in[i] = d_in[3 + i];
    k_prep<<<64, 256, 0, stream>>>(a, gp, wq, wf);
  }

  k_hist<<<gE, 256, 0, stream>>>(ei, cnt, deg, rank);
  k_scan1<<<nb, 1024, 0, stream>>>(cnt, off, bsum);
  k_scan23<<<nb, 1024, 0, stream>>>(off, bsum, deg, dis, nb);
  k_place<<<gE, 256, 0, stream>>>(ei, off, rank, crow, ceid);
  k_asum<<<(NN * 16 + 255) / 256, 256, 0, stream>>>(eattr, gp, asum, off, ceid);

  // ---- Xg = x @ Wx -> Bx
  {
    MArgs a = {};
    a.A0 = x; a.W0T = wq + OWXT; a.a0raw = 1;
    a.out = Bx; a.gp = gp; a.mode = 0;
    k_mgemm<0, 128, 128><<<gG1, 256, 0, stream>>>(a);
  }
  // ---- S = segsum(Xg[row]) -> Bt (ceid dead from here)
  k_spmm<0><<<gS, 256, 0, stream>>>(Bx, Bt, off, crow, nullptr, nullptr, 0, nullptr);
  // ---- h = (S + asum@We + cnt*b)/max(cnt,1) -> Bx
  {
    MArgs a = {};
    a.A0 = asum; a.W0T = wq + OWET;
    a.bias = wf + 0; a.G = Bt; a.out = Bx; a.cnt = cnt; a.gp = gp; a.mode = 2;
    k_mgemm<0, 32, 128><<<gG1, 256, 0, stream>>>(a);
  }

  // ---- preprocess: z = h@Wpre + b -> Bt (+partials); BN params -> abA (h never materialized)
  {
    MArgs a = {};
    a.A0 = Bx; a.W0T = wq + OWPRE;
    a.bias = wf + 128; a.out = Bt; a.gp = gp; a.part = part; a.mode = 0;
    k_mgemm<0, 128, 128><<<gG1, 256, 0, stream>>>(a);
  }
  k_red<<<8, 256, 0, stream>>>(part, statA, gG1);
  k_bnfin<<<1, 128, 0, stream>>>(statA, wf + 256, wf + 384, abA);

  // ---- cheb1: T1 = lhat(relu(bn(z))) -> Bx  (BN fused into gather)
  k_spmm<1><<<gS, 256, 0, stream>>>(Bt, Bx, off, crow, dis, nullptr, 0, abA);
  // dual: G = bn(z)@WD1 + T1@W11 + b -> Bt ; P = T1@V21 -> Bx  (BN fused into A0 stage)
  {
    MArgs a = {};
    a.A0 = Bt; a.W0T = wq + OWD1; a.bnab = abA;
    a.A1 = Bx; a.W1T = wq + OW11;
    a.W2T = wq + OV21; a.out2 = Bx;
    a.bias = wf + 512; a.out = Bt; a.gp = gp; a.mode = 0;
    k_mgemm<1, 128, 64><<<gG2, 256, 0, stream>>>(a);
  }
  // h2 = relu(G + lhat(P)) -> Bt
  k_spmm<0><<<gS, 256, 0, stream>>>(Bx, Bt, off, crow, dis, Bt, 1, nullptr);

  // ---- cheb2: T1' = lhat(h2) -> Bx
  k_spmm<0><<<gS, 256, 0, stream>>>(Bt, Bx, off, crow, dis, nullptr, 0, nullptr);
  {
    MArgs a = {};
    a.A0 = Bt; a.W0T = wq + OWD2;
    a.A1 = Bx; a.W1T = wq + OW12;
    a.W2T = wq + OV22; a.out2 = Bx;
    a.bias = wf + 640; a.out = Bt; a.gp = gp; a.mode = 0;
    k_mgemm<1, 128, 64><<<gG2, 256, 0, stream>>>(a);
  }
  // h3 = relu(G + lhat(P')) -> Bt
  k_spmm<0><<<gS, 256, 0, stream>>>(Bx, Bt, off, crow, dis, Bt, 1, nullptr);

  // ---- postprocess: z2 = h3@Wpost + b -> Bx (+partials) ; fused BN+relu+dot -> y
  {
    MArgs a = {};
    a.A0 = Bt; a.W0T = wq + OWPOST;
    a.bias = wf + 768; a.out = Bx; a.gp = gp; a.part = part; a.mode = 0;
    k_mgemm<0, 128, 128><<<gG1, 256, 0, stream>>>(a);
  }
  k_red<<<8, 256, 0, stream>>>(part, statB, gG1);
  k_bnfin<<<1, 128, 0, stream>>>(statB, wf + 896, wf + 1024, abB);
  k_out<<<(NN + 3) / 4, 256, 0, stream>>>(Bx, abB, wf + 1152, wf + 1280, gp, d_out);
}

// Round 10
// 809.566 us; speedup vs baseline: 1.0670x; 1.0670x over previous
//
#include <hip/hip_runtime.h>
#include <hip/hip_bf16.h>

using u16 = unsigned short;
using u32 = unsigned int;

#define NN 100000
#define NE 1000000

typedef __attribute__((ext_vector_type(8))) short bfrag;
typedef __attribute__((ext_vector_type(4))) float ffrag;

#define BF16ONE2 0x3F803F80u

__device__ __forceinline__ float bf2f(u16 u) { return __uint_as_float(((u32)u) << 16); }
__device__ __forceinline__ u16 f2bf(float f) {
  u32 x = __float_as_uint(f);
  return (u16)((x + 0x7fffu + ((x >> 16) & 1u)) >> 16);
}
__device__ __forceinline__ float rdv(const void* p, long i, int f) {
  return f ? bf2f(((const u16*)p)[i]) : ((const float*)p)[i];
}
__device__ __forceinline__ void acc8(float* a, uint4 v, float w) {
  a[0] = fmaf(w, __uint_as_float(v.x << 16), a[0]);
  a[1] = fmaf(w, __uint_as_float(v.x & 0xffff0000u), a[1]);
  a[2] = fmaf(w, __uint_as_float(v.y << 16), a[2]);
  a[3] = fmaf(w, __uint_as_float(v.y & 0xffff0000u), a[3]);
  a[4] = fmaf(w, __uint_as_float(v.z << 16), a[4]);
  a[5] = fmaf(w, __uint_as_float(v.z & 0xffff0000u), a[5]);
  a[6] = fmaf(w, __uint_as_float(v.w << 16), a[6]);
  a[7] = fmaf(w, __uint_as_float(v.w & 0xffff0000u), a[7]);
}

// wq (u16) element offsets
#define OWXT 0
#define OWPRE 16384
#define OWD1 32768
#define OW11 49152
#define OV21 65536
#define OWD2 81920
#define OW12 98304
#define OV22 114688
#define OWPOST 131072
#define OWET 147456

struct PrepArgs { const void* in[16]; };

__global__ void k_prep(PrepArgs a, const u32* __restrict__ gp, u16* __restrict__ wq,
                       float* __restrict__ wf) {
  int t = blockIdx.x * 256 + threadIdx.x;
  int f = (gp[0] == BF16ONE2) ? 1 : 0;
  if (t < 16384) {
    int o = t >> 7, k = t & 127;
    int ko = k * 128 + o;
    int ok = o * 128 + k;
    wq[OWXT + ok] = f2bf(rdv(a.in[0], ko, f));
    wq[OWPRE + ok] = f2bf(rdv(a.in[2], ko, f));
    float c0 = rdv(a.in[6], ko, f);
    float c1 = rdv(a.in[6], 16384 + ko, f);
    float c2 = rdv(a.in[6], 32768 + ko, f);
    wq[OWD1 + ok] = f2bf(c0 - c2);
    wq[OW11 + ok] = f2bf(c1);
    wq[OV21 + ok] = f2bf(2.f * c2);
    float d0 = rdv(a.in[8], ko, f);
    float d1 = rdv(a.in[8], 16384 + ko, f);
    float d2 = rdv(a.in[8], 32768 + ko, f);
    wq[OWD2 + ok] = f2bf(d0 - d2);
    wq[OW12 + ok] = f2bf(d1);
    wq[OV22 + ok] = f2bf(2.f * d2);
    wq[OWPOST + ok] = f2bf(rdv(a.in[10], ko, f));
  }
  if (t < 4096) {
    int o = t >> 5, k = t & 31;
    wq[OWET + o * 32 + k] = (k < 16) ? f2bf(rdv(a.in[0], (long)(128 + k) * 128 + o, f)) : (u16)0;
  }
  if (t < 1281) {
    int s = t >> 7, j = t & 127;
    const int map[11] = {1, 3, 4, 5, 7, 9, 11, 12, 13, 14, 15};
    wf[t] = rdv(a.in[map[s]], j, f);
  }
}

// ---------------- histogram (fire-and-forget atomics, full occupancy) ----------------
__global__ void k_hist(const int* __restrict__ ei, int* cnt, int* deg) {
  int e = blockIdx.x * 256 + threadIdx.x;
  if (e >= NE) return;
  atomicAdd(&deg[ei[e]], 1);
  atomicAdd(&cnt[ei[NE + e]], 1);
}

// ---------------- exclusive scan ----------------
__global__ void k_scan1(const int* __restrict__ cnt, int* off, int* bsum) {
  __shared__ int s[1024];
  int t = threadIdx.x;
  int g = blockIdx.x * 1024 + t;
  int v = (g < NN) ? cnt[g] : 0;
  s[t] = v;
  __syncthreads();
  for (int st = 1; st < 1024; st <<= 1) {
    int x = (t >= st) ? s[t - st] : 0;
    __syncthreads();
    s[t] += x;
    __syncthreads();
  }
  if (g < NN) off[g] = s[t] - v;
  if (t == 1023) bsum[blockIdx.x] = s[t];
}

__global__ void k_scan23(int* off, const int* __restrict__ bsum,
                         const int* __restrict__ deg, float* __restrict__ dis, int nb) {
  __shared__ int s[128];
  int t = threadIdx.x;
  int v = 0;
  if (t < 128) {
    v = (t < nb) ? bsum[t] : 0;
    s[t] = v;
  }
  __syncthreads();
  for (int st = 1; st < 128; st <<= 1) {
    int x = (t >= st && t < 128) ? s[t - st] : 0;
    __syncthreads();
    if (t < 128) s[t] += x;
    __syncthreads();
  }
  if (t < 128) s[t] -= v;
  __syncthreads();
  int pre = s[blockIdx.x];
  int g = blockIdx.x * 1024 + t;
  if (g < NN) {
    off[g] += pre;
    int d = deg[g];
    dis[g] = d > 0 ? rsqrtf((float)d) : 0.f;
  }
  if (g == 0) off[NN] = NE;
}

// ---------------- CSR placement ----------------
__global__ void k_place(const int* __restrict__ ei, const int* __restrict__ off,
                        int* cur, int* crow, int* ceid) {
  int e = blockIdx.x * 256 + threadIdx.x;
  if (e >= NE) return;
  int r = ei[e], c = ei[NE + e];
  int p = off[c] + atomicAdd(&cur[c], 1);
  crow[p] = r;
  ceid[p] = e;
}

// ------------- SpMM: 2 nodes/wave, 2 half-chains x 16 lanes x uint4; w = cnorm[p] -------------
__global__ __launch_bounds__(256) void k_spmm(const u16* __restrict__ src,
                                              u16* __restrict__ dst,
                                              const int* __restrict__ off,
                                              const int* __restrict__ crow,
                                              const float* __restrict__ cnorm,
                                              const u16* __restrict__ G, int relu) {
  int t = threadIdx.x;
  int node = blockIdx.x * 8 + (t >> 5);
  if (node >= NN) return;
  int l = t & 31;
  int half = l >> 4;
  int c = (l & 15) * 8;
  int p0 = off[node], p1 = off[node + 1];
  float a[8];
#pragma unroll
  for (int j = 0; j < 8; j++) a[j] = 0.f;
  const u16* sp = src + c;
  if (cnorm) {
    int p = p0 + half;
    for (; p + 6 < p1; p += 8) {
      int r0 = crow[p], r1 = crow[p + 2], r2 = crow[p + 4], r3 = crow[p + 6];
      float w0 = cnorm[p], w1 = cnorm[p + 2], w2 = cnorm[p + 4], w3 = cnorm[p + 6];
      uint4 v0 = *(const uint4*)(sp + (long)r0 * 128);
      uint4 v1 = *(const uint4*)(sp + (long)r1 * 128);
      uint4 v2 = *(const uint4*)(sp + (long)r2 * 128);
      uint4 v3 = *(const uint4*)(sp + (long)r3 * 128);
      acc8(a, v0, w0);
      acc8(a, v1, w1);
      acc8(a, v2, w2);
      acc8(a, v3, w3);
    }
    for (; p < p1; p += 2) {
      acc8(a, *(const uint4*)(sp + (long)crow[p] * 128), cnorm[p]);
    }
  } else {
    int p = p0 + half;
    for (; p + 6 < p1; p += 8) {
      int r0 = crow[p], r1 = crow[p + 2], r2 = crow[p + 4], r3 = crow[p + 6];
      uint4 v0 = *(const uint4*)(sp + (long)r0 * 128);
      uint4 v1 = *(const uint4*)(sp + (long)r1 * 128);
      uint4 v2 = *(const uint4*)(sp + (long)r2 * 128);
      uint4 v3 = *(const uint4*)(sp + (long)r3 * 128);
      acc8(a, v0, 1.f);
      acc8(a, v1, 1.f);
      acc8(a, v2, 1.f);
      acc8(a, v3, 1.f);
    }
    for (; p < p1; p += 2) acc8(a, *(const uint4*)(sp + (long)crow[p] * 128), 1.f);
  }
#pragma unroll
  for (int j = 0; j < 8; j++) a[j] += __shfl_xor(a[j], 16);
  if (half) return;
  if (G) acc8(a, *(const uint4*)(G + (long)node * 128 + c), 1.f);
  if (relu) {
#pragma unroll
    for (int j = 0; j < 8; j++) a[j] = fmaxf(a[j], 0.f);
  }
  uint4 o;
  o.x = (u32)f2bf(a[0]) | ((u32)f2bf(a[1]) << 16);
  o.y = (u32)f2bf(a[2]) | ((u32)f2bf(a[3]) << 16);
  o.z = (u32)f2bf(a[4]) | ((u32)f2bf(a[5]) << 16);
  o.w = (u32)f2bf(a[6]) | ((u32)f2bf(a[7]) << 16);
  *(uint4*)(dst + (long)node * 128 + c) = o;
}

// ------------- edge_attr segment-sum ([N,16]) + cnorm precompute -------------
__global__ __launch_bounds__(256) void k_asum(const void* __restrict__ eattr,
                                              const u32* __restrict__ gp,
                                              u16* __restrict__ asum,
                                              const int* __restrict__ off,
                                              const int* __restrict__ ceid,
                                              const int* __restrict__ crow,
                                              const float* __restrict__ dis,
                                              float* __restrict__ cnorm) {
  int t = blockIdx.x * 256 + threadIdx.x;
  int node = t >> 4;
  if (node >= NN) return;
  int j = t & 15;
  int p0 = off[node], p1 = off[node + 1];
  // cnorm: 16 threads of this node split the CSR slice
  float ndis = -dis[node];
  for (int p = p0 + j; p < p1; p += 16) cnorm[p] = ndis * dis[crow[p]];
  float a = 0.f;
  if (gp[0] == BF16ONE2) {
    const u16* e16 = (const u16*)eattr;
    int p = p0;
    for (; p + 4 <= p1; p += 4) {
      float v0 = bf2f(e16[(long)ceid[p] * 16 + j]);
      float v1 = bf2f(e16[(long)ceid[p + 1] * 16 + j]);
      float v2 = bf2f(e16[(long)ceid[p + 2] * 16 + j]);
      float v3 = bf2f(e16[(long)ceid[p + 3] * 16 + j]);
      a += v0 + v1 + v2 + v3;
    }
    for (; p < p1; p++) a += bf2f(e16[(long)ceid[p] * 16 + j]);
  } else {
    const float* e32 = (const float*)eattr;
    int p = p0;
    for (; p + 4 <= p1; p += 4) {
      float v0 = e32[(long)ceid[p] * 16 + j];
      float v1 = e32[(long)ceid[p + 1] * 16 + j];
      float v2 = e32[(long)ceid[p + 2] * 16 + j];
      float v3 = e32[(long)ceid[p + 3] * 16 + j];
      a += v0 + v1 + v2 + v3;
    }
    for (; p < p1; p++) a += e32[(long)ceid[p] * 16 + j];
  }
  asum[(long)node * 16 + j] = f2bf(a);
}

// ------------- MFMA GEMM, weight-stationary regs + LDS-staged A -------------
struct MArgs {
  const void* A0; const u16* W0T; int a0raw;
  const u16* A1; const u16* W1T;
  const u16* W2T; u16* out2;
  const float* bias;
  u16* out;
  const u32* gp;
  float* part;
};

#define ASTRIDE 136
#define ESTRIDE 132

template <int DUAL, int K0, int ROWS>
__global__ __launch_bounds__(256) void k_mgemm(MArgs m) {
  constexpr int RT = ROWS / 16;
  constexpr int TPR = 256 / ROWS;
  constexpr int SEGW = K0 / TPR;
  constexpr int NKB0 = K0 / 32;
  __shared__ __align__(16) u16 sA[ROWS * ASTRIDE];
  int tid = threadIdx.x;
  int wv = tid >> 6, lane = tid & 63;
  int col16 = lane & 15, quad = lane >> 4;
  int r0 = blockIdx.x * ROWS;

  ffrag acc[RT * 2];
#pragma unroll
  for (int i = 0; i < RT * 2; i++)
#pragma unroll
    for (int g = 0; g < 4; g++) acc[i][g] = 0.f;

  {
    int row = tid / TPR, seg = tid % TPR;
    int ra = r0 + row;
    if (ra >= NN) ra = NN - 1;
    bool f32a = m.a0raw && (m.gp[0] != BF16ONE2);
    if (f32a) {
      const float* gs = (const float*)m.A0 + (long)ra * K0 + seg * SEGW;
      u32* lp = (u32*)(sA + row * ASTRIDE + seg * SEGW);
#pragma unroll
      for (int e = 0; e < SEGW / 8; e++) {
        float4 v0 = *(const float4*)(gs + e * 8);
        float4 v1 = *(const float4*)(gs + e * 8 + 4);
        lp[e * 4 + 0] = (u32)f2bf(v0.x) | ((u32)f2bf(v0.y) << 16);
        lp[e * 4 + 1] = (u32)f2bf(v0.z) | ((u32)f2bf(v0.w) << 16);
        lp[e * 4 + 2] = (u32)f2bf(v1.x) | ((u32)f2bf(v1.y) << 16);
        lp[e * 4 + 3] = (u32)f2bf(v1.z) | ((u32)f2bf(v1.w) << 16);
      }
    } else {
      const u16* gs = (const u16*)m.A0 + (long)ra * K0 + seg * SEGW;
      uint4* lp = (uint4*)(sA + row * ASTRIDE + seg * SEGW);
#pragma unroll
      for (int e = 0; e < SEGW / 8; e++) lp[e] = *(const uint4*)(gs + e * 8);
    }
  }
  bfrag b0[2][NKB0];
#pragma unroll
  for (int c = 0; c < 2; c++)
#pragma unroll
    for (int kb = 0; kb < NKB0; kb++)
      b0[c][kb] = *(const bfrag*)(m.W0T + (long)(wv * 32 + c * 16 + col16) * K0 + kb * 32 + quad * 8);
  __syncthreads();
#pragma unroll
  for (int kb = 0; kb < NKB0; kb++)
#pragma unroll
    for (int rt = 0; rt < RT; rt++) {
      bfrag af = *(const bfrag*)(sA + (rt * 16 + col16) * ASTRIDE + kb * 32 + quad * 8);
      acc[rt * 2 + 0] = __builtin_amdgcn_mfma_f32_16x16x32_bf16(af, b0[0][kb], acc[rt * 2 + 0], 0, 0, 0);
      acc[rt * 2 + 1] = __builtin_amdgcn_mfma_f32_16x16x32_bf16(af, b0[1][kb], acc[rt * 2 + 1], 0, 0, 0);
    }

  ffrag acc2[DUAL ? RT * 2 : 1];
  if constexpr (DUAL) {
#pragma unroll
    for (int i = 0; i < RT * 2; i++)
#pragma unroll
      for (int g = 0; g < 4; g++) acc2[i][g] = 0.f;
    __syncthreads();
    {
      int row = tid / TPR, seg = tid % TPR;
      int ra = r0 + row;
      if (ra >= NN) ra = NN - 1;
      const u16* gs = m.A1 + (long)ra * 128 + seg * SEGW;
      uint4* lp = (uint4*)(sA + row * ASTRIDE + seg * SEGW);
#pragma unroll
      for (int e = 0; e < SEGW / 8; e++) lp[e] = *(const uint4*)(gs + e * 8);
    }
    bfrag b1[2][4], b2[2][4];
#pragma unroll
    for (int c = 0; c < 2; c++)
#pragma unroll
      for (int kb = 0; kb < 4; kb++) {
        b1[c][kb] = *(const bfrag*)(m.W1T + (long)(wv * 32 + c * 16 + col16) * 128 + kb * 32 + quad * 8);
        b2[c][kb] = *(const bfrag*)(m.W2T + (long)(wv * 32 + c * 16 + col16) * 128 + kb * 32 + quad * 8);
      }
    __syncthreads();
#pragma unroll
    for (int kb = 0; kb < 4; kb++)
#pragma unroll
      for (int rt = 0; rt < RT; rt++) {
        bfrag af = *(const bfrag*)(sA + (rt * 16 + col16) * ASTRIDE + kb * 32 + quad * 8);
        acc[rt * 2 + 0] = __builtin_amdgcn_mfma_f32_16x16x32_bf16(af, b1[0][kb], acc[rt * 2 + 0], 0, 0, 0);
        acc[rt * 2 + 1] = __builtin_amdgcn_mfma_f32_16x16x32_bf16(af, b1[1][kb], acc[rt * 2 + 1], 0, 0, 0);
        acc2[rt * 2 + 0] = __builtin_amdgcn_mfma_f32_16x16x32_bf16(af, b2[0][kb], acc2[rt * 2 + 0], 0, 0, 0);
        acc2[rt * 2 + 1] = __builtin_amdgcn_mfma_f32_16x16x32_bf16(af, b2[1][kb], acc2[rt * 2 + 1], 0, 0, 0);
      }
  }

  __syncthreads();
#pragma unroll
  for (int rt = 0; rt < RT; rt++)
#pragma unroll
    for (int c = 0; c < 2; c++) {
      int col = wv * 32 + c * 16 + col16;
      float bj = m.bias ? m.bias[col] : 0.f;
#pragma unroll
      for (int g = 0; g < 4; g++)
        sA[(rt * 16 + quad * 4 + g) * ESTRIDE + col] = f2bf(acc[rt * 2 + c][g] + bj);
    }
  __syncthreads();
  {
    constexpr int CPT = 128 / TPR;
    int rr = tid / TPR, d = tid % TPR;
    int rowg = r0 + rr;
    if (rowg < NN) {
      const u16* sp2 = sA + rr * ESTRIDE + d * CPT;
      uint4* o = (uint4*)(m.out + (long)rowg * 128 + d * CPT);
#pragma unroll
      for (int e = 0; e < CPT / 8; e++) {
        const uint2* s2 = (const uint2*)(sp2 + e * 8);
        uint2 lo = s2[0], hi = s2[1];
        o[e] = make_uint4(lo.x, lo.y, hi.x, hi.y);
      }
    }
  }
  if (m.part) {
    __shared__ float ps[256], pq[256];
    int col = tid & 127, hf = tid >> 7;
    float s = 0.f, q = 0.f;
#pragma unroll
    for (int r = 0; r < ROWS / 2; r++) {
      int rr = hf * (ROWS / 2) + r;
      if (r0 + rr < NN) {
        float v = bf2f(sA[rr * ESTRIDE + col]);
        s += v;
        q += v * v;
      }
    }
    ps[tid] = s;
    pq[tid] = q;
    __syncthreads();
    if (tid < 128) {
      m.part[(long)blockIdx.x * 256 + tid] = ps[tid] + ps[tid + 128];
      m.part[(long)blockIdx.x * 256 + 128 + tid] = pq[tid] + pq[tid + 128];
    }
  }
  if constexpr (DUAL) {
    __syncthreads();
#pragma unroll
    for (int rt = 0; rt < RT; rt++)
#pragma unroll
      for (int c = 0; c < 2; c++) {
        int col = wv * 32 + c * 16 + col16;
#pragma unroll
        for (int g = 0; g < 4; g++)
          sA[(rt * 16 + quad * 4 + g) * ESTRIDE + col] = f2bf(acc2[rt * 2 + c][g]);
      }
    __syncthreads();
    constexpr int CPT = 128 / TPR;
    int rr = tid / TPR, d = tid % TPR;
    int rowg = r0 + rr;
    if (rowg < NN) {
      const u16* sp2 = sA + rr * ESTRIDE + d * CPT;
      uint4* o = (uint4*)(m.out2 + (long)rowg * 128 + d * CPT);
#pragma unroll
      for (int e = 0; e < CPT / 8; e++) {
        const uint2* s2 = (const uint2*)(sp2 + e * 8);
        uint2 lo = s2[0], hi = s2[1];
        o[e] = make_uint4(lo.x, lo.y, hi.x, hi.y);
      }
    }
  }
}

// ------------- fused ET + preprocess GEMM (h never hits HBM) -------------
// h = (S + asum@We^T + cnt*b_int)/max(cnt,1);  z = h@Wpre^T + b_pre -> out (+partials)
__global__ __launch_bounds__(256) void k_etpre(const u16* __restrict__ asum,
                                               const u16* __restrict__ Wet,
                                               const u16* __restrict__ Wpre,
                                               const float* __restrict__ b_int,
                                               const float* __restrict__ b_pre,
                                               const u16* __restrict__ G,
                                               const int* __restrict__ cnt,
                                               u16* __restrict__ out, float* part) {
  __shared__ __align__(16) u16 sA[64 * ASTRIDE];
  int tid = threadIdx.x;
  int wv = tid >> 6, lane = tid & 63;
  int col16 = lane & 15, quad = lane >> 4;
  int r0 = blockIdx.x * 64;

  // stage asum [64 x 16] into sA cols 0..15; zero cols 16..31
  {
    int row = tid >> 2, seg = tid & 3;
    int ra = r0 + row;
    if (ra >= NN) ra = NN - 1;
    if (seg < 2) {
      *(uint4*)(sA + row * ASTRIDE + seg * 8) = *(const uint4*)(asum + (long)ra * 16 + seg * 8);
    } else {
      *(uint4*)(sA + row * ASTRIDE + seg * 8) = make_uint4(0, 0, 0, 0);
    }
  }
  bfrag be[2];
#pragma unroll
  for (int c = 0; c < 2; c++)
    be[c] = *(const bfrag*)(Wet + (long)(wv * 32 + c * 16 + col16) * 32 + quad * 8);
  __syncthreads();
  ffrag acc[8];
#pragma unroll
  for (int i = 0; i < 8; i++)
#pragma unroll
    for (int g = 0; g < 4; g++) acc[i][g] = 0.f;
#pragma unroll
  for (int rt = 0; rt < 4; rt++) {
    bfrag af = *(const bfrag*)(sA + (rt * 16 + col16) * ASTRIDE + quad * 8);
    acc[rt * 2 + 0] = __builtin_amdgcn_mfma_f32_16x16x32_bf16(af, be[0], acc[rt * 2 + 0], 0, 0, 0);
    acc[rt * 2 + 1] = __builtin_amdgcn_mfma_f32_16x16x32_bf16(af, be[1], acc[rt * 2 + 1], 0, 0, 0);
  }
  __syncthreads();
  // h epilogue -> sA (ASTRIDE layout, full 128 cols)
#pragma unroll
  for (int rt = 0; rt < 4; rt++)
#pragma unroll
    for (int c = 0; c < 2; c++) {
      int col = wv * 32 + c * 16 + col16;
      float bj = b_int[col];
#pragma unroll
      for (int g = 0; g < 4; g++) {
        int r = r0 + rt * 16 + quad * 4 + g;
        float v = acc[rt * 2 + c][g];
        int cc = 0;
        if (r < NN) {
          v += bf2f(G[(long)r * 128 + col]);
          cc = cnt[r];
        }
        v = (v + (float)cc * bj) / (float)(cc > 1 ? cc : 1);
        sA[(rt * 16 + quad * 4 + g) * ASTRIDE + col] = f2bf(v);
      }
    }
  bfrag b1[2][4];
#pragma unroll
  for (int c = 0; c < 2; c++)
#pragma unroll
    for (int kb = 0; kb < 4; kb++)
      b1[c][kb] = *(const bfrag*)(Wpre + (long)(wv * 32 + c * 16 + col16) * 128 + kb * 32 + quad * 8);
  __syncthreads();
  ffrag a2[8];
#pragma unroll
  for (int i = 0; i < 8; i++)
#pragma unroll
    for (int g = 0; g < 4; g++) a2[i][g] = 0.f;
#pragma unroll
  for (int kb = 0; kb < 4; kb++)
#pragma unroll
    for (int rt = 0; rt < 4; rt++) {
      bfrag af = *(const bfrag*)(sA + (rt * 16 + col16) * ASTRIDE + kb * 32 + quad * 8);
      a2[rt * 2 + 0] = __builtin_amdgcn_mfma_f32_16x16x32_bf16(af, b1[0][kb], a2[rt * 2 + 0], 0, 0, 0);
      a2[rt * 2 + 1] = __builtin_amdgcn_mfma_f32_16x16x32_bf16(af, b1[1][kb], a2[rt * 2 + 1], 0, 0, 0);
    }
  __syncthreads();
#pragma unroll
  for (int rt = 0; rt < 4; rt++)
#pragma unroll
    for (int c = 0; c < 2; c++) {
      int col = wv * 32 + c * 16 + col16;
      float bj = b_pre[col];
#pragma unroll
      for (int g = 0; g < 4; g++)
        sA[(rt * 16 + quad * 4 + g) * ESTRIDE + col] = f2bf(a2[rt * 2 + c][g] + bj);
    }
  __syncthreads();
  {
    int rr = tid >> 2, d = tid & 3;
    int rowg = r0 + rr;
    if (rowg < NN) {
      const u16* sp2 = sA + rr * ESTRIDE + d * 32;
      uint4* o = (uint4*)(out + (long)rowg * 128 + d * 32);
#pragma unroll
      for (int e = 0; e < 4; e++) {
        const uint2* s2 = (const uint2*)(sp2 + e * 8);
        uint2 lo = s2[0], hi = s2[1];
        o[e] = make_uint4(lo.x, lo.y, hi.x, hi.y);
      }
    }
  }
  {
    __shared__ float ps[256], pq[256];
    int col = tid & 127, hf = tid >> 7;
    float s = 0.f, q = 0.f;
#pragma unroll
    for (int r = 0; r < 32; r++) {
      int rr = hf * 32 + r;
      if (r0 + rr < NN) {
        float v = bf2f(sA[rr * ESTRIDE + col]);
        s += v;
        q += v * v;
      }
    }
    ps[tid] = s;
    pq[tid] = q;
    __syncthreads();
    if (tid < 128) {
      part[(long)blockIdx.x * 256 + tid] = ps[tid] + ps[tid + 128];
      part[(long)blockIdx.x * 256 + 128 + tid] = pq[tid] + pq[tid + 128];
    }
  }
}

// ------------- reduce partials + BN finalize fused (8 blocks x 16 cols) -------------
__global__ void k_redfin(const float* __restrict__ part, const float* __restrict__ gamma,
                         const float* __restrict__ beta, float* ab, int nblk) {
  int tid = threadIdx.x;
  int col = blockIdx.x * 16 + (tid & 15);
  int ch = tid >> 4;  // 16 chunks
  float s = 0.f, q = 0.f;
  for (int b = ch; b < nblk; b += 16) {
    s += part[(long)b * 256 + col];
    q += part[(long)b * 256 + 128 + col];
  }
  __shared__ float sh[256], qh[256];
  sh[tid] = s;
  qh[tid] = q;
  __syncthreads();
  if (tid < 16) {
    float ts = 0.f, tq = 0.f;
#pragma unroll
    for (int i = 0; i < 16; i++) {
      ts += sh[i * 16 + tid];
      tq += qh[i * 16 + tid];
    }
    int j = blockIdx.x * 16 + tid;
    float m = ts * (1.f / (float)NN);
    float v = fmaxf(tq * (1.f / (float)NN) - m * m, 0.f);
    float a = gamma[j] * rsqrtf(v + 1e-5f);
    ab[j] = a;
    ab[128 + j] = beta[j] - m * a;
  }
}

__global__ void k_bnrelu(const u16* __restrict__ z, u16* __restrict__ out,
                         const float* __restrict__ ab) {
  long idx = (long)blockIdx.x * 256 + threadIdx.x;
  long t = idx * 2;
  if (t >= (long)NN * 128) return;
  int col = (int)(t & 127);
  u32 v = *(const u32*)(z + t);
  float f0 = fmaxf(__uint_as_float(v << 16) * ab[col] + ab[128 + col], 0.f);
  float f1 = fmaxf(__uint_as_float(v & 0xffff0000u) * ab[col + 1] + ab[129 + col], 0.f);
  *(u32*)(out + t) = (u32)f2bf(f0) | ((u32)f2bf(f1) << 16);
}

__global__ void k_out(const u16* __restrict__ z, const float* __restrict__ ab,
                      const float* __restrict__ wout, const float* __restrict__ bout,
                      const u32* __restrict__ gp, void* __restrict__ y) {
  int node = blockIdx.x * 4 + (threadIdx.x >> 6);
  if (node >= NN) return;
  int lane = threadIdx.x & 63;
  float s = 0.f;
#pragma unroll
  for (int c = lane; c < 128; c += 64) {
    float zz = bf2f(z[(long)node * 128 + c]);
    float h = fmaxf(ab[c] * zz + ab[128 + c], 0.f);
    s += h * wout[c];
  }
#pragma unroll
  for (int o = 32; o > 0; o >>= 1) s += __shfl_down(s, o);
  if (lane == 0) {
    float r = s + bout[0];
    if (gp[0] == BF16ONE2) ((u16*)y)[node] = f2bf(r);
    else ((float*)y)[node] = r;
  }
}

extern "C" void kernel_launch(void* const* d_in, const int* in_sizes, int n_in,
                              void* d_out, int out_size, void* d_ws, size_t ws_size,
                              hipStream_t stream) {
  const void* x = d_in[0];
  const int* ei = (const int*)d_in[1];
  const void* eattr = d_in[2];
  const u32* gp = (const u32*)d_in[7];
  (void)in_sizes; (void)n_in; (void)out_size; (void)ws_size;

  char* w = (char*)d_ws;
  size_t p = 0;
  auto alloc = [&](size_t b) { size_t r = p; p += (b + 255) & ~(size_t)255; return r; };
  size_t o_cnt = alloc((size_t)NN * 4);
  size_t o_deg = alloc((size_t)NN * 4);
  size_t o_cur = alloc((size_t)NN * 4);
  size_t o_zero_end = p;
  size_t o_dis = alloc((size_t)NN * 4);
  size_t o_off = alloc((size_t)(NN + 1) * 4);
  size_t o_bsum = alloc(1024 * 4);
  size_t o_ab = alloc(512 * 4);
  size_t o_wq = alloc((size_t)151552 * 2);
  size_t o_wf = alloc((size_t)1281 * 4);
  size_t o_crow = alloc((size_t)NE * 4);
  size_t o_cnrm = alloc((size_t)NE * 4);
  size_t o_asum = alloc((size_t)NN * 16 * 2);
  size_t o_part = alloc((size_t)1563 * 256 * 4);
  size_t o_Bx = alloc((size_t)NN * 128 * 2);
  size_t o_Bt = alloc((size_t)NN * 128 * 2);
  // ~66.5 MB

  int* cnt = (int*)(w + o_cnt);
  int* deg = (int*)(w + o_deg);
  int* cur = (int*)(w + o_cur);
  float* dis = (float*)(w + o_dis);
  int* off = (int*)(w + o_off);
  int* bsum = (int*)(w + o_bsum);
  float* abA = (float*)(w + o_ab);
  float* abB = abA + 256;
  u16* wq = (u16*)(w + o_wq);
  float* wf = (float*)(w + o_wf);
  int* crow = (int*)(w + o_crow);
  float* cnrm = (float*)(w + o_cnrm);
  u16* asum = (u16*)(w + o_asum);
  float* part = (float*)(w + o_part);
  u16* Bx = (u16*)(w + o_Bx);
  u16* Bt = (u16*)(w + o_Bt);
  int* ceid = (int*)Bt;  // transient: dead before Bt first written (after k_asum)

  hipMemsetAsync(w + o_cnt, 0, o_zero_end - o_cnt, stream);

  int gE = (NE + 255) / 256;
  int nb = (NN + 1023) / 1024;
  int gS = (NN + 7) / 8;
  int gG1 = (NN + 127) / 128;  // 782
  int gG2 = (NN + 63) / 64;    // 1563

  {
    PrepArgs a;
    for (int i = 0; i < 16; i++) a.in[i] = d_in[3 + i];
    k_prep<<<64, 256, 0, stream>>>(a, gp, wq, wf);
  }

  k_hist<<<gE, 256, 0, stream>>>(ei, cnt, deg);
  k_scan1<<<nb, 1024, 0, stream>>>(cnt, off, bsum);
  k_scan23<<<nb, 1024, 0, stream>>>(off, bsum, deg, dis, nb);
  k_place<<<gE, 256, 0, stream>>>(ei, off, cur, crow, ceid);
  k_asum<<<(NN * 16 + 255) / 256, 256, 0, stream>>>(eattr, gp, asum, off, ceid, crow, dis, cnrm);

  // ---- Xg = x @ Wx -> Bx
  {
    MArgs a = {};
    a.A0 = x; a.W0T = wq + OWXT; a.a0raw = 1;
    a.out = Bx; a.gp = gp;
    k_mgemm<0, 128, 128><<<gG1, 256, 0, stream>>>(a);
  }
  // ---- S = segsum(Xg[row]) -> Bt (ceid dead from here)
  k_spmm<<<gS, 256, 0, stream>>>(Bx, Bt, off, crow, nullptr, nullptr, 0);
  // ---- fused: h=(S+asum@We+cnt*b)/cnt (LDS only), z=h@Wpre+b -> Bt (+partials)
  k_etpre<<<gG2, 256, 0, stream>>>(asum, wq + OWET, wq + OWPRE, wf + 0, wf + 128,
                                   Bt, cnt, Bt, part);
  k_redfin<<<8, 256, 0, stream>>>(part, wf + 256, wf + 384, abA, gG2);
  k_bnrelu<<<(int)(((long)NN * 128 / 2 + 255) / 256), 256, 0, stream>>>(Bt, Bx, abA);

  // ---- cheb1
  k_spmm<<<gS, 256, 0, stream>>>(Bx, Bt, off, crow, cnrm, nullptr, 0);
  {
    MArgs a = {};
    a.A0 = Bx; a.W0T = wq + OWD1;
    a.A1 = Bt; a.W1T = wq + OW11;
    a.W2T = wq + OV21; a.out2 = Bt;
    a.bias = wf + 512; a.out = Bx; a.gp = gp;
    k_mgemm<1, 128, 64><<<gG2, 256, 0, stream>>>(a);
  }
  k_spmm<<<gS, 256, 0, stream>>>(Bt, Bx, off, crow, cnrm, Bx, 1);

  // ---- cheb2
  k_spmm<<<gS, 256, 0, stream>>>(Bx, Bt, off, crow, cnrm, nullptr, 0);
  {
    MArgs a = {};
    a.A0 = Bx; a.W0T = wq + OWD2;
    a.A1 = Bt; a.W1T = wq + OW12;
    a.W2T = wq + OV22; a.out2 = Bt;
    a.bias = wf + 640; a.out = Bx; a.gp = gp;
    k_mgemm<1, 128, 64><<<gG2, 256, 0, stream>>>(a);
  }
  k_spmm<<<gS, 256, 0, stream>>>(Bt, Bx, off, crow, cnrm, Bx, 1);

  // ---- postprocess (+partials) + output
  {
    MArgs a = {};
    a.A0 = Bx; a.W0T = wq + OWPOST;
    a.bias = wf + 768; a.out = Bt; a.gp = gp; a.part = part;
    k_mgemm<0, 128, 128><<<gG1, 256, 0, stream>>>(a);
  }
  k_redfin<<<8, 256, 0, stream>>>(part, wf + 896, wf + 1024, abB, gG1);
  k_out<<<(NN + 3) / 4, 256, 0, stream>>>(Bt, abB, wf + 1152, wf + 1280, gp, d_out);
}

// Round 11
// 758.950 us; speedup vs baseline: 1.1382x; 1.0667x over previous
//
#include <hip/hip_runtime.h>
#include <hip/hip_bf16.h>

using u16 = unsigned short;
using u32 = unsigned int;

#define NN 100000
#define NE 1000000

typedef __attribute__((ext_vector_type(8))) short bfrag;
typedef __attribute__((ext_vector_type(4))) float ffrag;

#define BF16ONE2 0x3F803F80u

__device__ __forceinline__ float bf2f(u16 u) { return __uint_as_float(((u32)u) << 16); }
__device__ __forceinline__ u16 f2bf(float f) {
  u32 x = __float_as_uint(f);
  return (u16)((x + 0x7fffu + ((x >> 16) & 1u)) >> 16);
}
__device__ __forceinline__ float rdv(const void* p, long i, int f) {
  return f ? bf2f(((const u16*)p)[i]) : ((const float*)p)[i];
}
__device__ __forceinline__ void acc8(float* a, uint4 v, float w) {
  a[0] = fmaf(w, __uint_as_float(v.x << 16), a[0]);
  a[1] = fmaf(w, __uint_as_float(v.x & 0xffff0000u), a[1]);
  a[2] = fmaf(w, __uint_as_float(v.y << 16), a[2]);
  a[3] = fmaf(w, __uint_as_float(v.y & 0xffff0000u), a[3]);
  a[4] = fmaf(w, __uint_as_float(v.z << 16), a[4]);
  a[5] = fmaf(w, __uint_as_float(v.z & 0xffff0000u), a[5]);
  a[6] = fmaf(w, __uint_as_float(v.w << 16), a[6]);
  a[7] = fmaf(w, __uint_as_float(v.w & 0xffff0000u), a[7]);
}

// wq (u16) element offsets
#define OWXT 0
#define OWPRE 16384
#define OWD1 32768
#define OW11 49152
#define OV21 65536
#define OWD2 81920
#define OW12 98304
#define OV22 114688
#define OWPOST 131072
#define OWET 147456

#define ASTRIDE 136
#define ESTRIDE 132

struct PrepArgs { const void* in[16]; };

__global__ void k_prep(PrepArgs a, const u32* __restrict__ gp, u16* __restrict__ wq,
                       float* __restrict__ wf) {
  int t = blockIdx.x * 256 + threadIdx.x;
  int f = (gp[0] == BF16ONE2) ? 1 : 0;
  if (t < 16384) {
    int o = t >> 7, k = t & 127;
    int ko = k * 128 + o;
    int ok = o * 128 + k;
    wq[OWXT + ok] = f2bf(rdv(a.in[0], ko, f));
    wq[OWPRE + ok] = f2bf(rdv(a.in[2], ko, f));
    float c0 = rdv(a.in[6], ko, f);
    float c1 = rdv(a.in[6], 16384 + ko, f);
    float c2 = rdv(a.in[6], 32768 + ko, f);
    wq[OWD1 + ok] = f2bf(c0 - c2);
    wq[OW11 + ok] = f2bf(c1);
    wq[OV21 + ok] = f2bf(2.f * c2);
    float d0 = rdv(a.in[8], ko, f);
    float d1 = rdv(a.in[8], 16384 + ko, f);
    float d2 = rdv(a.in[8], 32768 + ko, f);
    wq[OWD2 + ok] = f2bf(d0 - d2);
    wq[OW12 + ok] = f2bf(d1);
    wq[OV22 + ok] = f2bf(2.f * d2);
    wq[OWPOST + ok] = f2bf(rdv(a.in[10], ko, f));
  }
  if (t < 4096) {
    int o = t >> 5, k = t & 31;
    wq[OWET + o * 32 + k] = (k < 16) ? f2bf(rdv(a.in[0], (long)(128 + k) * 128 + o, f)) : (u16)0;
  }
  if (t < 1281) {
    int s = t >> 7, j = t & 127;
    const int map[11] = {1, 3, 4, 5, 7, 9, 11, 12, 13, 14, 15};
    wf[t] = rdv(a.in[map[s]], j, f);
  }
}

// ---------------- histogram (fire-and-forget atomics, full occupancy) ----------------
__global__ void k_hist(const int* __restrict__ ei, int* cnt, int* deg) {
  int e = blockIdx.x * 256 + threadIdx.x;
  if (e >= NE) return;
  atomicAdd(&deg[ei[e]], 1);
  atomicAdd(&cnt[ei[NE + e]], 1);
}

// ---------------- exclusive scan ----------------
__global__ void k_scan1(const int* __restrict__ cnt, int* off, int* bsum) {
  __shared__ int s[1024];
  int t = threadIdx.x;
  int g = blockIdx.x * 1024 + t;
  int v = (g < NN) ? cnt[g] : 0;
  s[t] = v;
  __syncthreads();
  for (int st = 1; st < 1024; st <<= 1) {
    int x = (t >= st) ? s[t - st] : 0;
    __syncthreads();
    s[t] += x;
    __syncthreads();
  }
  if (g < NN) off[g] = s[t] - v;
  if (t == 1023) bsum[blockIdx.x] = s[t];
}

__global__ void k_scan23(int* off, const int* __restrict__ bsum,
                         const int* __restrict__ deg, float* __restrict__ dis, int nb) {
  __shared__ int s[128];
  int t = threadIdx.x;
  int v = 0;
  if (t < 128) {
    v = (t < nb) ? bsum[t] : 0;
    s[t] = v;
  }
  __syncthreads();
  for (int st = 1; st < 128; st <<= 1) {
    int x = (t >= st && t < 128) ? s[t - st] : 0;
    __syncthreads();
    if (t < 128) s[t] += x;
    __syncthreads();
  }
  if (t < 128) s[t] -= v;
  __syncthreads();
  int pre = s[blockIdx.x];
  int g = blockIdx.x * 1024 + t;
  if (g < NN) {
    off[g] += pre;
    int d = deg[g];
    dis[g] = d > 0 ? rsqrtf((float)d) : 0.f;
  }
  if (g == 0) off[NN] = NE;
}

// ---------------- CSR placement ----------------
__global__ void k_place(const int* __restrict__ ei, const int* __restrict__ off,
                        int* cur, int* crow, int* ceid) {
  int e = blockIdx.x * 256 + threadIdx.x;
  if (e >= NE) return;
  int r = ei[e], c = ei[NE + e];
  int p = off[c] + atomicAdd(&cur[c], 1);
  crow[p] = r;
  ceid[p] = e;
}

// ------------- standalone SpMM (weighted): dst = L(src) -------------
__global__ __launch_bounds__(256) void k_spmm(const u16* __restrict__ src,
                                              u16* __restrict__ dst,
                                              const int* __restrict__ off,
                                              const int* __restrict__ crow,
                                              const float* __restrict__ cnorm) {
  int t = threadIdx.x;
  int node = blockIdx.x * 8 + (t >> 5);
  if (node >= NN) return;
  int l = t & 31;
  int half = l >> 4;
  int c = (l & 15) * 8;
  int p0 = off[node], p1 = off[node + 1];
  float a[8];
#pragma unroll
  for (int j = 0; j < 8; j++) a[j] = 0.f;
  const u16* sp = src + c;
  int p = p0 + half;
  for (; p + 6 < p1; p += 8) {
    int r0 = crow[p], r1 = crow[p + 2], r2 = crow[p + 4], r3 = crow[p + 6];
    float w0 = cnorm[p], w1 = cnorm[p + 2], w2 = cnorm[p + 4], w3 = cnorm[p + 6];
    uint4 v0 = *(const uint4*)(sp + (long)r0 * 128);
    uint4 v1 = *(const uint4*)(sp + (long)r1 * 128);
    uint4 v2 = *(const uint4*)(sp + (long)r2 * 128);
    uint4 v3 = *(const uint4*)(sp + (long)r3 * 128);
    acc8(a, v0, w0);
    acc8(a, v1, w1);
    acc8(a, v2, w2);
    acc8(a, v3, w3);
  }
  for (; p < p1; p += 2) acc8(a, *(const uint4*)(sp + (long)crow[p] * 128), cnorm[p]);
#pragma unroll
  for (int j = 0; j < 8; j++) a[j] += __shfl_xor(a[j], 16);
  if (half) return;
  uint4 o;
  o.x = (u32)f2bf(a[0]) | ((u32)f2bf(a[1]) << 16);
  o.y = (u32)f2bf(a[2]) | ((u32)f2bf(a[3]) << 16);
  o.z = (u32)f2bf(a[4]) | ((u32)f2bf(a[5]) << 16);
  o.w = (u32)f2bf(a[6]) | ((u32)f2bf(a[7]) << 16);
  *(uint4*)(dst + (long)node * 128 + c) = o;
}

// ------------- gather L(src) (or segsum) for 64 rows into LDS (ASTRIDE layout) -------------
template <int WEIGHTED>
__device__ __forceinline__ void gather_lds(u16* sA, const u16* __restrict__ src,
                                           const int* __restrict__ off,
                                           const int* __restrict__ crow,
                                           const float* __restrict__ cnorm, int r0) {
  int tid = threadIdx.x;
  int grp = tid >> 4;      // 16 groups of 16 lanes
  int c = (tid & 15) * 8;  // 8 cols per lane
  const u16* sp = src + c;
#pragma unroll
  for (int i = 0; i < 4; i++) {
    int nl = grp * 4 + i;
    int node = r0 + nl;
    float a[8];
#pragma unroll
    for (int j = 0; j < 8; j++) a[j] = 0.f;
    if (node < NN) {
      int p0 = off[node], p1 = off[node + 1];
      int p = p0;
      for (; p + 4 <= p1; p += 4) {
        int r0i = crow[p], r1i = crow[p + 1], r2i = crow[p + 2], r3i = crow[p + 3];
        float w0 = WEIGHTED ? cnorm[p] : 1.f;
        float w1 = WEIGHTED ? cnorm[p + 1] : 1.f;
        float w2 = WEIGHTED ? cnorm[p + 2] : 1.f;
        float w3 = WEIGHTED ? cnorm[p + 3] : 1.f;
        uint4 v0 = *(const uint4*)(sp + (long)r0i * 128);
        uint4 v1 = *(const uint4*)(sp + (long)r1i * 128);
        uint4 v2 = *(const uint4*)(sp + (long)r2i * 128);
        uint4 v3 = *(const uint4*)(sp + (long)r3i * 128);
        acc8(a, v0, w0);
        acc8(a, v1, w1);
        acc8(a, v2, w2);
        acc8(a, v3, w3);
      }
      for (; p < p1; p++)
        acc8(a, *(const uint4*)(sp + (long)crow[p] * 128), WEIGHTED ? cnorm[p] : 1.f);
    }
    uint4 o;
    o.x = (u32)f2bf(a[0]) | ((u32)f2bf(a[1]) << 16);
    o.y = (u32)f2bf(a[2]) | ((u32)f2bf(a[3]) << 16);
    o.z = (u32)f2bf(a[4]) | ((u32)f2bf(a[5]) << 16);
    o.w = (u32)f2bf(a[6]) | ((u32)f2bf(a[7]) << 16);
    *(uint4*)(sA + nl * ASTRIDE + c) = o;
  }
}

// ------------- edge_attr segment-sum ([N,16]) + cnorm precompute -------------
__global__ __launch_bounds__(256) void k_asum(const void* __restrict__ eattr,
                                              const u32* __restrict__ gp,
                                              u16* __restrict__ asum,
                                              const int* __restrict__ off,
                                              const int* __restrict__ ceid,
                                              const int* __restrict__ crow,
                                              const float* __restrict__ dis,
                                              float* __restrict__ cnorm) {
  int t = blockIdx.x * 256 + threadIdx.x;
  int node = t >> 4;
  if (node >= NN) return;
  int j = t & 15;
  int p0 = off[node], p1 = off[node + 1];
  float ndis = -dis[node];
  for (int p = p0 + j; p < p1; p += 16) cnorm[p] = ndis * dis[crow[p]];
  float a = 0.f;
  if (gp[0] == BF16ONE2) {
    const u16* e16 = (const u16*)eattr;
    int p = p0;
    for (; p + 4 <= p1; p += 4) {
      float v0 = bf2f(e16[(long)ceid[p] * 16 + j]);
      float v1 = bf2f(e16[(long)ceid[p + 1] * 16 + j]);
      float v2 = bf2f(e16[(long)ceid[p + 2] * 16 + j]);
      float v3 = bf2f(e16[(long)ceid[p + 3] * 16 + j]);
      a += v0 + v1 + v2 + v3;
    }
    for (; p < p1; p++) a += bf2f(e16[(long)ceid[p] * 16 + j]);
  } else {
    const float* e32 = (const float*)eattr;
    int p = p0;
    for (; p + 4 <= p1; p += 4) {
      float v0 = e32[(long)ceid[p] * 16 + j];
      float v1 = e32[(long)ceid[p + 1] * 16 + j];
      float v2 = e32[(long)ceid[p + 2] * 16 + j];
      float v3 = e32[(long)ceid[p + 3] * 16 + j];
      a += v0 + v1 + v2 + v3;
    }
    for (; p < p1; p++) a += e32[(long)ceid[p] * 16 + j];
  }
  asum[(long)node * 16 + j] = f2bf(a);
}

// ------------- plain MFMA GEMM (ROWS=128): out = A0@W0T^T + bias (+partials) -------------
struct MArgs {
  const void* A0; const u16* W0T; int a0raw;
  const float* bias;
  u16* out;
  const u32* gp;
  float* part;
};

__global__ __launch_bounds__(256) void k_mgemm(MArgs m) {
  constexpr int ROWS = 128, RT = 8, TPR = 2, SEGW = 64;
  __shared__ __align__(16) u16 sA[ROWS * ASTRIDE];
  int tid = threadIdx.x;
  int wv = tid >> 6, lane = tid & 63;
  int col16 = lane & 15, quad = lane >> 4;
  int r0 = blockIdx.x * ROWS;

  ffrag acc[RT * 2];
#pragma unroll
  for (int i = 0; i < RT * 2; i++)
#pragma unroll
    for (int g = 0; g < 4; g++) acc[i][g] = 0.f;

  {
    int row = tid / TPR, seg = tid % TPR;
    int ra = r0 + row;
    if (ra >= NN) ra = NN - 1;
    bool f32a = m.a0raw && (m.gp[0] != BF16ONE2);
    if (f32a) {
      const float* gs = (const float*)m.A0 + (long)ra * 128 + seg * SEGW;
      u32* lp = (u32*)(sA + row * ASTRIDE + seg * SEGW);
#pragma unroll
      for (int e = 0; e < SEGW / 8; e++) {
        float4 v0 = *(const float4*)(gs + e * 8);
        float4 v1 = *(const float4*)(gs + e * 8 + 4);
        lp[e * 4 + 0] = (u32)f2bf(v0.x) | ((u32)f2bf(v0.y) << 16);
        lp[e * 4 + 1] = (u32)f2bf(v0.z) | ((u32)f2bf(v0.w) << 16);
        lp[e * 4 + 2] = (u32)f2bf(v1.x) | ((u32)f2bf(v1.y) << 16);
        lp[e * 4 + 3] = (u32)f2bf(v1.z) | ((u32)f2bf(v1.w) << 16);
      }
    } else {
      const u16* gs = (const u16*)m.A0 + (long)ra * 128 + seg * SEGW;
      uint4* lp = (uint4*)(sA + row * ASTRIDE + seg * SEGW);
#pragma unroll
      for (int e = 0; e < SEGW / 8; e++) lp[e] = *(const uint4*)(gs + e * 8);
    }
  }
  bfrag b0[2][4];
#pragma unroll
  for (int c = 0; c < 2; c++)
#pragma unroll
    for (int kb = 0; kb < 4; kb++)
      b0[c][kb] = *(const bfrag*)(m.W0T + (long)(wv * 32 + c * 16 + col16) * 128 + kb * 32 + quad * 8);
  __syncthreads();
#pragma unroll
  for (int kb = 0; kb < 4; kb++)
#pragma unroll
    for (int rt = 0; rt < RT; rt++) {
      bfrag af = *(const bfrag*)(sA + (rt * 16 + col16) * ASTRIDE + kb * 32 + quad * 8);
      acc[rt * 2 + 0] = __builtin_amdgcn_mfma_f32_16x16x32_bf16(af, b0[0][kb], acc[rt * 2 + 0], 0, 0, 0);
      acc[rt * 2 + 1] = __builtin_amdgcn_mfma_f32_16x16x32_bf16(af, b0[1][kb], acc[rt * 2 + 1], 0, 0, 0);
    }
  __syncthreads();
#pragma unroll
  for (int rt = 0; rt < RT; rt++)
#pragma unroll
    for (int c = 0; c < 2; c++) {
      int col = wv * 32 + c * 16 + col16;
      float bj = m.bias ? m.bias[col] : 0.f;
#pragma unroll
      for (int g = 0; g < 4; g++)
        sA[(rt * 16 + quad * 4 + g) * ESTRIDE + col] = f2bf(acc[rt * 2 + c][g] + bj);
    }
  __syncthreads();
  {
    int rr = tid / TPR, d = tid % TPR;
    int rowg = r0 + rr;
    if (rowg < NN) {
      const u16* sp2 = sA + rr * ESTRIDE + d * 64;
      uint4* o = (uint4*)(m.out + (long)rowg * 128 + d * 64);
#pragma unroll
      for (int e = 0; e < 8; e++) {
        const uint2* s2 = (const uint2*)(sp2 + e * 8);
        uint2 lo = s2[0], hi = s2[1];
        o[e] = make_uint4(lo.x, lo.y, hi.x, hi.y);
      }
    }
  }
  if (m.part) {
    __shared__ float ps[256], pq[256];
    int col = tid & 127, hf = tid >> 7;
    float s = 0.f, q = 0.f;
#pragma unroll
    for (int r = 0; r < 64; r++) {
      int rr = hf * 64 + r;
      if (r0 + rr < NN) {
        float v = bf2f(sA[rr * ESTRIDE + col]);
        s += v;
        q += v * v;
      }
    }
    ps[tid] = s;
    pq[tid] = q;
    __syncthreads();
    if (tid < 128) {
      m.part[(long)blockIdx.x * 256 + tid] = ps[tid] + ps[tid + 128];
      m.part[(long)blockIdx.x * 256 + 128 + tid] = pq[tid] + pq[tid + 128];
    }
  }
}

// ------------- fused: S-gather + ET GEMM + mean + preprocess GEMM -------------
__global__ __launch_bounds__(256) void k_etpre(const u16* __restrict__ Xg,
                                               const u16* __restrict__ asum,
                                               const u16* __restrict__ Wet,
                                               const u16* __restrict__ Wpre,
                                               const float* __restrict__ b_int,
                                               const float* __restrict__ b_pre,
                                               const int* __restrict__ off,
                                               const int* __restrict__ crow,
                                               const int* __restrict__ cnt,
                                               u16* __restrict__ out, float* part) {
  __shared__ __align__(16) u16 sA[64 * ASTRIDE];
  int tid = threadIdx.x;
  int wv = tid >> 6, lane = tid & 63;
  int col16 = lane & 15, quad = lane >> 4;
  int r0 = blockIdx.x * 64;

  // stage asum [64 x 16] into cols 0..15, zero 16..31
  {
    int row = tid >> 2, seg = tid & 3;
    int ra = r0 + row;
    if (ra >= NN) ra = NN - 1;
    if (seg < 2)
      *(uint4*)(sA + row * ASTRIDE + seg * 8) = *(const uint4*)(asum + (long)ra * 16 + seg * 8);
    else
      *(uint4*)(sA + row * ASTRIDE + seg * 8) = make_uint4(0, 0, 0, 0);
  }
  bfrag be[2];
#pragma unroll
  for (int c = 0; c < 2; c++)
    be[c] = *(const bfrag*)(Wet + (long)(wv * 32 + c * 16 + col16) * 32 + quad * 8);
  __syncthreads();
  ffrag accE[8];
#pragma unroll
  for (int i = 0; i < 8; i++)
#pragma unroll
    for (int g = 0; g < 4; g++) accE[i][g] = 0.f;
#pragma unroll
  for (int rt = 0; rt < 4; rt++) {
    bfrag af = *(const bfrag*)(sA + (rt * 16 + col16) * ASTRIDE + quad * 8);
    accE[rt * 2 + 0] = __builtin_amdgcn_mfma_f32_16x16x32_bf16(af, be[0], accE[rt * 2 + 0], 0, 0, 0);
    accE[rt * 2 + 1] = __builtin_amdgcn_mfma_f32_16x16x32_bf16(af, be[1], accE[rt * 2 + 1], 0, 0, 0);
  }
  __syncthreads();
  // gather S = segsum(Xg) into sA (full 128 cols)
  gather_lds<0>(sA, Xg, off, crow, nullptr, r0);
  __syncthreads();
  // h = (accE + S + cnt*b)/max(cnt,1)  -> in-place at C-layout positions
#pragma unroll
  for (int rt = 0; rt < 4; rt++)
#pragma unroll
    for (int c = 0; c < 2; c++) {
      int col = wv * 32 + c * 16 + col16;
      float bj = b_int[col];
#pragma unroll
      for (int g = 0; g < 4; g++) {
        int rr = rt * 16 + quad * 4 + g;
        int r = r0 + rr;
        float v = accE[rt * 2 + c][g] + bf2f(sA[rr * ASTRIDE + col]);
        int cc = (r < NN) ? cnt[r] : 0;
        v = (v + (float)cc * bj) / (float)(cc > 1 ? cc : 1);
        sA[rr * ASTRIDE + col] = f2bf(v);
      }
    }
  bfrag b1[2][4];
#pragma unroll
  for (int c = 0; c < 2; c++)
#pragma unroll
    for (int kb = 0; kb < 4; kb++)
      b1[c][kb] = *(const bfrag*)(Wpre + (long)(wv * 32 + c * 16 + col16) * 128 + kb * 32 + quad * 8);
  __syncthreads();
  ffrag a2[8];
#pragma unroll
  for (int i = 0; i < 8; i++)
#pragma unroll
    for (int g = 0; g < 4; g++) a2[i][g] = 0.f;
#pragma unroll
  for (int kb = 0; kb < 4; kb++)
#pragma unroll
    for (int rt = 0; rt < 4; rt++) {
      bfrag af = *(const bfrag*)(sA + (rt * 16 + col16) * ASTRIDE + kb * 32 + quad * 8);
      a2[rt * 2 + 0] = __builtin_amdgcn_mfma_f32_16x16x32_bf16(af, b1[0][kb], a2[rt * 2 + 0], 0, 0, 0);
      a2[rt * 2 + 1] = __builtin_amdgcn_mfma_f32_16x16x32_bf16(af, b1[1][kb], a2[rt * 2 + 1], 0, 0, 0);
    }
  __syncthreads();
#pragma unroll
  for (int rt = 0; rt < 4; rt++)
#pragma unroll
    for (int c = 0; c < 2; c++) {
      int col = wv * 32 + c * 16 + col16;
      float bj = b_pre[col];
#pragma unroll
      for (int g = 0; g < 4; g++)
        sA[(rt * 16 + quad * 4 + g) * ESTRIDE + col] = f2bf(a2[rt * 2 + c][g] + bj);
    }
  __syncthreads();
  {
    int rr = tid >> 2, d = tid & 3;
    int rowg = r0 + rr;
    if (rowg < NN) {
      const u16* sp2 = sA + rr * ESTRIDE + d * 32;
      uint4* o = (uint4*)(out + (long)rowg * 128 + d * 32);
#pragma unroll
      for (int e = 0; e < 4; e++) {
        const uint2* s2 = (const uint2*)(sp2 + e * 8);
        uint2 lo = s2[0], hi = s2[1];
        o[e] = make_uint4(lo.x, lo.y, hi.x, hi.y);
      }
    }
  }
  {
    __shared__ float ps[256], pq[256];
    int col = tid & 127, hf = tid >> 7;
    float s = 0.f, q = 0.f;
#pragma unroll
    for (int r = 0; r < 32; r++) {
      int rr = hf * 32 + r;
      if (r0 + rr < NN) {
        float v = bf2f(sA[rr * ESTRIDE + col]);
        s += v;
        q += v * v;
      }
    }
    ps[tid] = s;
    pq[tid] = q;
    __syncthreads();
    if (tid < 128) {
      part[(long)blockIdx.x * 256 + tid] = ps[tid] + ps[tid + 128];
      part[(long)blockIdx.x * 256 + 128 + tid] = pq[tid] + pq[tid + 128];
    }
  }
}

// ------------- fused cheb layer: out = relu(hb@WD + T1@W1 + L(T1)@V2 + b), in-place over hb -------------
__global__ __launch_bounds__(256) void k_cheb(const u16* __restrict__ hb,
                                              const u16* __restrict__ T1,
                                              const int* __restrict__ off,
                                              const int* __restrict__ crow,
                                              const float* __restrict__ cnorm,
                                              const u16* __restrict__ WD,
                                              const u16* __restrict__ W1,
                                              const u16* __restrict__ V2,
                                              const float* __restrict__ bias,
                                              u16* __restrict__ out) {
  __shared__ __align__(16) u16 sA[64 * ASTRIDE];
  int tid = threadIdx.x;
  int wv = tid >> 6, lane = tid & 63;
  int col16 = lane & 15, quad = lane >> 4;
  int r0 = blockIdx.x * 64;

  ffrag acc[8];
#pragma unroll
  for (int i = 0; i < 8; i++)
#pragma unroll
    for (int g = 0; g < 4; g++) acc[i][g] = 0.f;

  // phase 1: gather L(T1) -> sA ; MFMA with V2
  gather_lds<1>(sA, T1, off, crow, cnorm, r0);
  bfrag bv[2][4];
#pragma unroll
  for (int c = 0; c < 2; c++)
#pragma unroll
    for (int kb = 0; kb < 4; kb++)
      bv[c][kb] = *(const bfrag*)(V2 + (long)(wv * 32 + c * 16 + col16) * 128 + kb * 32 + quad * 8);
  __syncthreads();
#pragma unroll
  for (int kb = 0; kb < 4; kb++)
#pragma unroll
    for (int rt = 0; rt < 4; rt++) {
      bfrag af = *(const bfrag*)(sA + (rt * 16 + col16) * ASTRIDE + kb * 32 + quad * 8);
      acc[rt * 2 + 0] = __builtin_amdgcn_mfma_f32_16x16x32_bf16(af, bv[0][kb], acc[rt * 2 + 0], 0, 0, 0);
      acc[rt * 2 + 1] = __builtin_amdgcn_mfma_f32_16x16x32_bf16(af, bv[1][kb], acc[rt * 2 + 1], 0, 0, 0);
    }
  __syncthreads();

  // phase 2: stage hb own rows ; MFMA with WD
  {
    int row = tid >> 2, seg = tid & 3;
    int ra = r0 + row;
    if (ra >= NN) ra = NN - 1;
    const u16* gs = hb + (long)ra * 128 + seg * 32;
    uint4* lp = (uint4*)(sA + row * ASTRIDE + seg * 32);
#pragma unroll
    for (int e = 0; e < 4; e++) lp[e] = *(const uint4*)(gs + e * 8);
  }
#pragma unroll
  for (int c = 0; c < 2; c++)
#pragma unroll
    for (int kb = 0; kb < 4; kb++)
      bv[c][kb] = *(const bfrag*)(WD + (long)(wv * 32 + c * 16 + col16) * 128 + kb * 32 + quad * 8);
  __syncthreads();
#pragma unroll
  for (int kb = 0; kb < 4; kb++)
#pragma unroll
    for (int rt = 0; rt < 4; rt++) {
      bfrag af = *(const bfrag*)(sA + (rt * 16 + col16) * ASTRIDE + kb * 32 + quad * 8);
      acc[rt * 2 + 0] = __builtin_amdgcn_mfma_f32_16x16x32_bf16(af, bv[0][kb], acc[rt * 2 + 0], 0, 0, 0);
      acc[rt * 2 + 1] = __builtin_amdgcn_mfma_f32_16x16x32_bf16(af, bv[1][kb], acc[rt * 2 + 1], 0, 0, 0);
    }
  __syncthreads();

  // phase 3: stage T1 own rows ; MFMA with W1
  {
    int row = tid >> 2, seg = tid & 3;
    int ra = r0 + row;
    if (ra >= NN) ra = NN - 1;
    const u16* gs = T1 + (long)ra * 128 + seg * 32;
    uint4* lp = (uint4*)(sA + row * ASTRIDE + seg * 32);
#pragma unroll
    for (int e = 0; e < 4; e++) lp[e] = *(const uint4*)(gs + e * 8);
  }
#pragma unroll
  for (int c = 0; c < 2; c++)
#pragma unroll
    for (int kb = 0; kb < 4; kb++)
      bv[c][kb] = *(const bfrag*)(W1 + (long)(wv * 32 + c * 16 + col16) * 128 + kb * 32 + quad * 8);
  __syncthreads();
#pragma unroll
  for (int kb = 0; kb < 4; kb++)
#pragma unroll
    for (int rt = 0; rt < 4; rt++) {
      bfrag af = *(const bfrag*)(sA + (rt * 16 + col16) * ASTRIDE + kb * 32 + quad * 8);
      acc[rt * 2 + 0] = __builtin_amdgcn_mfma_f32_16x16x32_bf16(af, bv[0][kb], acc[rt * 2 + 0], 0, 0, 0);
      acc[rt * 2 + 1] = __builtin_amdgcn_mfma_f32_16x16x32_bf16(af, bv[1][kb], acc[rt * 2 + 1], 0, 0, 0);
    }
  __syncthreads();

  // epilogue: +bias, relu, repack, store
#pragma unroll
  for (int rt = 0; rt < 4; rt++)
#pragma unroll
    for (int c = 0; c < 2; c++) {
      int col = wv * 32 + c * 16 + col16;
      float bj = bias[col];
#pragma unroll
      for (int g = 0; g < 4; g++)
        sA[(rt * 16 + quad * 4 + g) * ESTRIDE + col] = f2bf(fmaxf(acc[rt * 2 + c][g] + bj, 0.f));
    }
  __syncthreads();
  {
    int rr = tid >> 2, d = tid & 3;
    int rowg = r0 + rr;
    if (rowg < NN) {
      const u16* sp2 = sA + rr * ESTRIDE + d * 32;
      uint4* o = (uint4*)(out + (long)rowg * 128 + d * 32);
#pragma unroll
      for (int e = 0; e < 4; e++) {
        const uint2* s2 = (const uint2*)(sp2 + e * 8);
        uint2 lo = s2[0], hi = s2[1];
        o[e] = make_uint4(lo.x, lo.y, hi.x, hi.y);
      }
    }
  }
}

// ------------- reduce partials + BN finalize fused -------------
__global__ void k_redfin(const float* __restrict__ part, const float* __restrict__ gamma,
                         const float* __restrict__ beta, float* ab, int nblk) {
  int tid = threadIdx.x;
  int col = blockIdx.x * 16 + (tid & 15);
  int ch = tid >> 4;
  float s = 0.f, q = 0.f;
  for (int b = ch; b < nblk; b += 16) {
    s += part[(long)b * 256 + col];
    q += part[(long)b * 256 + 128 + col];
  }
  __shared__ float sh[256], qh[256];
  sh[tid] = s;
  qh[tid] = q;
  __syncthreads();
  if (tid < 16) {
    float ts = 0.f, tq = 0.f;
#pragma unroll
    for (int i = 0; i < 16; i++) {
      ts += sh[i * 16 + tid];
      tq += qh[i * 16 + tid];
    }
    int j = blockIdx.x * 16 + tid;
    float m = ts * (1.f / (float)NN);
    float v = fmaxf(tq * (1.f / (float)NN) - m * m, 0.f);
    float a = gamma[j] * rsqrtf(v + 1e-5f);
    ab[j] = a;
    ab[128 + j] = beta[j] - m * a;
  }
}

__global__ void k_bnrelu(const u16* __restrict__ z, u16* __restrict__ out,
                         const float* __restrict__ ab) {
  long idx = (long)blockIdx.x * 256 + threadIdx.x;
  long t = idx * 2;
  if (t >= (long)NN * 128) return;
  int col = (int)(t & 127);
  u32 v = *(const u32*)(z + t);
  float f0 = fmaxf(__uint_as_float(v << 16) * ab[col] + ab[128 + col], 0.f);
  float f1 = fmaxf(__uint_as_float(v & 0xffff0000u) * ab[col + 1] + ab[129 + col], 0.f);
  *(u32*)(out + t) = (u32)f2bf(f0) | ((u32)f2bf(f1) << 16);
}

__global__ void k_out(const u16* __restrict__ z, const float* __restrict__ ab,
                      const float* __restrict__ wout, const float* __restrict__ bout,
                      const u32* __restrict__ gp, void* __restrict__ y) {
  int node = blockIdx.x * 4 + (threadIdx.x >> 6);
  if (node >= NN) return;
  int lane = threadIdx.x & 63;
  float s = 0.f;
#pragma unroll
  for (int c = lane; c < 128; c += 64) {
    float zz = bf2f(z[(long)node * 128 + c]);
    float h = fmaxf(ab[c] * zz + ab[128 + c], 0.f);
    s += h * wout[c];
  }
#pragma unroll
  for (int o = 32; o > 0; o >>= 1) s += __shfl_down(s, o);
  if (lane == 0) {
    float r = s + bout[0];
    if (gp[0] == BF16ONE2) ((u16*)y)[node] = f2bf(r);
    else ((float*)y)[node] = r;
  }
}

extern "C" void kernel_launch(void* const* d_in, const int* in_sizes, int n_in,
                              void* d_out, int out_size, void* d_ws, size_t ws_size,
                              hipStream_t stream) {
  const void* x = d_in[0];
  const int* ei = (const int*)d_in[1];
  const void* eattr = d_in[2];
  const u32* gp = (const u32*)d_in[7];
  (void)in_sizes; (void)n_in; (void)out_size; (void)ws_size;

  char* w = (char*)d_ws;
  size_t p = 0;
  auto alloc = [&](size_t b) { size_t r = p; p += (b + 255) & ~(size_t)255; return r; };
  size_t o_cnt = alloc((size_t)NN * 4);
  size_t o_deg = alloc((size_t)NN * 4);
  size_t o_cur = alloc((size_t)NN * 4);
  size_t o_zero_end = p;
  size_t o_dis = alloc((size_t)NN * 4);
  size_t o_off = alloc((size_t)(NN + 1) * 4);
  size_t o_bsum = alloc(1024 * 4);
  size_t o_ab = alloc(512 * 4);
  size_t o_wq = alloc((size_t)151552 * 2);
  size_t o_wf = alloc((size_t)1281 * 4);
  size_t o_crow = alloc((size_t)NE * 4);
  size_t o_cnrm = alloc((size_t)NE * 4);
  size_t o_asum = alloc((size_t)NN * 16 * 2);
  size_t o_part = alloc((size_t)1563 * 256 * 4);
  size_t o_Bx = alloc((size_t)NN * 128 * 2);
  size_t o_Bt = alloc((size_t)NN * 128 * 2);

  int* cnt = (int*)(w + o_cnt);
  int* deg = (int*)(w + o_deg);
  int* cur = (int*)(w + o_cur);
  float* dis = (float*)(w + o_dis);
  int* off = (int*)(w + o_off);
  int* bsum = (int*)(w + o_bsum);
  float* abA = (float*)(w + o_ab);
  float* abB = abA + 256;
  u16* wq = (u16*)(w + o_wq);
  float* wf = (float*)(w + o_wf);
  int* crow = (int*)(w + o_crow);
  float* cnrm = (float*)(w + o_cnrm);
  u16* asum = (u16*)(w + o_asum);
  float* part = (float*)(w + o_part);
  u16* Bx = (u16*)(w + o_Bx);
  u16* Bt = (u16*)(w + o_Bt);
  int* ceid = (int*)Bt;  // transient: dead before Bt first written

  hipMemsetAsync(w + o_cnt, 0, o_zero_end - o_cnt, stream);

  int gE = (NE + 255) / 256;
  int nb = (NN + 1023) / 1024;
  int gS = (NN + 7) / 8;
  int gG1 = (NN + 127) / 128;  // 782
  int gG2 = (NN + 63) / 64;    // 1563

  {
    PrepArgs a;
    for (int i = 0; i < 16; i++) a.in[i] = d_in[3 + i];
    k_prep<<<64, 256, 0, stream>>>(a, gp, wq, wf);
  }

  k_hist<<<gE, 256, 0, stream>>>(ei, cnt, deg);
  k_scan1<<<nb, 1024, 0, stream>>>(cnt, off, bsum);
  k_scan23<<<nb, 1024, 0, stream>>>(off, bsum, deg, dis, nb);
  k_place<<<gE, 256, 0, stream>>>(ei, off, cur, crow, ceid);
  k_asum<<<(NN * 16 + 255) / 256, 256, 0, stream>>>(eattr, gp, asum, off, ceid, crow, dis, cnrm);

  // ---- Xg = x @ Wx -> Bx (must materialize: gather src)
  {
    MArgs a = {};
    a.A0 = x; a.W0T = wq + OWXT; a.a0raw = 1;
    a.out = Bx; a.gp = gp;
    k_mgemm<<<gG1, 256, 0, stream>>>(a);
  }
  // ---- fused: S = segsum(Xg) (gather in-kernel), h = (S+asum@We+cnt*b)/cnt, z = h@Wpre+b -> Bt
  k_etpre<<<gG2, 256, 0, stream>>>(Bx, asum, wq + OWET, wq + OWPRE, wf + 0, wf + 128,
                                   off, crow, cnt, Bt, part);
  k_redfin<<<8, 256, 0, stream>>>(part, wf + 256, wf + 384, abA, gG2);
  // ---- hb = relu(bn(z)): Bt -> Bx
  k_bnrelu<<<(int)(((long)NN * 128 / 2 + 255) / 256), 256, 0, stream>>>(Bt, Bx, abA);

  // ---- cheb1: T1 = L(hb) -> Bt ; fused h2 = relu(hb@WD1 + T1@W11 + L(T1)@V21 + b) -> Bx
  k_spmm<<<gS, 256, 0, stream>>>(Bx, Bt, off, crow, cnrm);
  k_cheb<<<gG2, 256, 0, stream>>>(Bx, Bt, off, crow, cnrm,
                                  wq + OWD1, wq + OW11, wq + OV21, wf + 512, Bx);

  // ---- cheb2
  k_spmm<<<gS, 256, 0, stream>>>(Bx, Bt, off, crow, cnrm);
  k_cheb<<<gG2, 256, 0, stream>>>(Bx, Bt, off, crow, cnrm,
                                  wq + OWD2, wq + OW12, wq + OV22, wf + 640, Bx);

  // ---- postprocess: z2 = h3@Wpost + b -> Bt (+partials) ; BN+relu+dot -> y
  {
    MArgs a = {};
    a.A0 = Bx; a.W0T = wq + OWPOST;
    a.bias = wf + 768; a.out = Bt; a.gp = gp; a.part = part;
    k_mgemm<<<gG1, 256, 0, stream>>>(a);
  }
  k_redfin<<<8, 256, 0, stream>>>(part, wf + 896, wf + 1024, abB, gG1);
  k_out<<<(NN + 3) / 4, 256, 0, stream>>>(Bt, abB, wf + 1152, wf + 1280, gp, d_out);
}